// Round 18
// baseline (187.580 us; speedup 1.0000x reference)
//
#include <hip/hip_runtime.h>
#include <hip/hip_bf16.h>

// GATv2 link predictor: N=50000, E=800000 (+N self loops), IN=128, HID=32, HEADS=4, OUT=64
// f32 in/out. CSR + fused GAT layers, shift-invariant softmax, pk-f16 logit math, f32 accum.
// bf16 MFMA projections: swapped operand, B-fragments read DIRECTLY from the pre-swizzled
// global W image (64KB, L2-hot) — no LDS staging (round-17's 64KB LDS capped occupancy at
// 2 blocks/CU and starved the fused degree-count blocks; VALUBusy was 3%).
// XCD-partitioned scatter; cur seeded by scanC.

#define DEVFN __device__ __forceinline__

typedef __attribute__((ext_vector_type(4))) float f32x4;
typedef __attribute__((ext_vector_type(8))) short bf16x8;
typedef _Float16 f16x2 __attribute__((ext_vector_type(2)));
typedef _Float16 f16x8 __attribute__((ext_vector_type(8)));

DEVFN unsigned short f2bf(float f) {  // RNE f32->bf16
  unsigned u = __float_as_uint(f);
  return (unsigned short)((u + 0x7fffu + ((u >> 16) & 1u)) >> 16);
}

DEVFN f16x2 pkrtz(float a, float b) {
  auto r = __builtin_amdgcn_cvt_pkrtz(a, b);
  union { decltype(r) s; f16x2 d; } u;
  u.s = r;
  return u.d;
}

template <int CTRL>
DEVFN float dpp_add(float s) {
  int x = __builtin_amdgcn_update_dpp(0, __float_as_int(s), CTRL, 0xF, 0xF, true);
  return s + __int_as_float(x);
}
template <int OFF>
DEVFN float swz_add(float s) {
  int x = __builtin_amdgcn_ds_swizzle(__float_as_int(s), OFF);
  return s + __int_as_float(x);
}

DEVFN bf16x8 load_frag(const float* p) {
  f32x4 u = *(const f32x4*)p;
  f32x4 v = *(const f32x4*)(p + 4);
  union { unsigned r[4]; bf16x8 h; } o;
  asm("v_cvt_pk_bf16_f32 %0, %1, %2" : "=v"(o.r[0]) : "v"(u[0]), "v"(u[1]));
  asm("v_cvt_pk_bf16_f32 %0, %1, %2" : "=v"(o.r[1]) : "v"(u[2]), "v"(u[3]));
  asm("v_cvt_pk_bf16_f32 %0, %1, %2" : "=v"(o.r[2]) : "v"(v[0]), "v"(v[1]));
  asm("v_cvt_pk_bf16_f32 %0, %1, %2" : "=v"(o.r[3]) : "v"(v[2]), "v"(v[3]));
  return o.h;
}
DEVFN bf16x8 load_frag(const unsigned short* p) { return *(const bf16x8*)p; }

// ---------------- prep0: W->bf16 swizzled image + zero cnt ----------------
__global__ __launch_bounds__(256) void prep0(const float* __restrict__ W1l,
                                             const float* __restrict__ W1r,
                                             const float* __restrict__ W2l,
                                             const float* __restrict__ W2r,
                                             unsigned short* __restrict__ wbuf,
                                             int4* __restrict__ cnt4, int n4) {
  int t = blockIdx.x * 256 + threadIdx.x;
  if (t < 16384) {  // W1: [128][128]
    int k = t >> 7, o = t & 127;
    unsigned off = ((unsigned)(o * 256 + k * 2)) ^ ((unsigned)(o & 7) << 4);
    wbuf[off >> 1] = f2bf(W1l[t]);
    wbuf[16384 + (off >> 1)] = f2bf(W1r[t]);
  }
  if (t < 8192) {  // W2: [128][64]
    int k = t >> 6, o = t & 63;
    unsigned off = ((unsigned)(o * 256 + k * 2)) ^ ((unsigned)(o & 7) << 4);
    wbuf[32768 + (off >> 1)] = f2bf(W2l[t]);
    wbuf[40960 + (off >> 1)] = f2bf(W2r[t]);
  }
  if (t < n4) cnt4[t] = make_int4(0, 0, 0, 0);
}

// ---------------- projdeg: proj1 (MFMA, no LDS) + degree count, fused dispatch -------------
__global__ __launch_bounds__(256) void projdeg(const float* __restrict__ X,
                                               const unsigned short* __restrict__ wsrc,
                                               const float* __restrict__ Ba,
                                               const float* __restrict__ Bb,
                                               _Float16* __restrict__ Ya,
                                               _Float16* __restrict__ Yb, int Mtiles, int pBlocks,
                                               const int* __restrict__ ei, int* __restrict__ cnt,
                                               int E, int ET) {
  constexpr int DOUT = 128;
  constexpr int NPM = DOUT / 16;
  constexpr unsigned MATB = DOUT * 256;
  if (blockIdx.x >= pBlocks) {  // degree-count blocks (no LDS, full occupancy)
    int t = (blockIdx.x - pBlocks) * 256 + threadIdx.x;
    if (t < ET) {
      int dst = (t < E) ? ei[E + t] : (t - E);
      atomicAdd(&cnt[dst], 1);
    }
    return;
  }
  const int t = threadIdx.x;
  const int l = t & 63, wv = t >> 6;
  const int mt = blockIdx.x * 4 + wv;
  if (mt >= Mtiles) return;
  const int r15 = l & 15, kq = l >> 4;

  bf16x8 a0[4];
  {
    const float* px = X + ((size_t)(mt * 16 + r15)) * 128 + kq * 8;
#pragma unroll
    for (int ks = 0; ks < 4; ++ks) a0[ks] = load_frag(px + ks * 32);
  }

  for (int nt = 0; nt < 2 * NPM; ++nt) {
    const int mat = nt / NPM;
    const int o = (nt % NPM) * 16 + r15;
    bf16x8 b[4];
#pragma unroll
    for (int ks = 0; ks < 4; ++ks) {
      unsigned byteoff =
          (((unsigned)(o * 256 + (ks * 32 + kq * 8) * 2)) ^ ((unsigned)(o & 7) << 4)) +
          (unsigned)mat * MATB;
      b[ks] = *(const bf16x8*)((const char*)wsrc + byteoff);  // L2-hot 64KB image
    }
    f32x4 c0 = {0.f, 0.f, 0.f, 0.f};
#pragma unroll
    for (int ks = 0; ks < 4; ++ks)
      c0 = __builtin_amdgcn_mfma_f32_16x16x32_bf16(b[ks], a0[ks], c0, 0, 0, 0);
    _Float16* Y = mat ? Yb : Ya;
    const float* Bv = mat ? Bb : Ba;
    const int obase = (nt % NPM) * 16 + 4 * kq;
    float4 b4 = *(const float4*)(Bv + obase);
    union { f16x2 h[2]; uint2 u; } pk;
    pk.h[0] = pkrtz(c0[0] + b4.x, c0[1] + b4.y);
    pk.h[1] = pkrtz(c0[2] + b4.z, c0[3] + b4.w);
    *(uint2*)(Y + (size_t)(mt * 16 + r15) * DOUT + obase) = pk.u;
  }
}

// ---------------- CSR scan: 3-kernel parallel version ----------------
__global__ __launch_bounds__(256) void scanA(const int* __restrict__ cnt, int* __restrict__ part,
                                             int N) {
  int i = blockIdx.x * 256 + threadIdx.x;
  int v = (i < N) ? cnt[i] : 0;
  __shared__ int wsm[4];
  int lane = threadIdx.x & 63, wid = threadIdx.x >> 6;
#pragma unroll
  for (int o = 1; o < 64; o <<= 1) v += __shfl_xor(v, o);
  if (lane == 0) wsm[wid] = v;
  __syncthreads();
  if (threadIdx.x == 0) part[blockIdx.x] = wsm[0] + wsm[1] + wsm[2] + wsm[3];
}

__global__ __launch_bounds__(256) void scanB(int* __restrict__ part, int* __restrict__ rowptr,
                                             int Bs, int N) {
  int t = threadIdx.x;
  int v = (t < Bs) ? part[t] : 0;
  int lane = t & 63, wid = t >> 6;
  int s = v;
#pragma unroll
  for (int o = 1; o < 64; o <<= 1) {
    int u = __shfl_up(s, o);
    if (lane >= o) s += u;
  }
  __shared__ int wsm[4];
  if (lane == 63) wsm[wid] = s;
  __syncthreads();
  int woff = 0;
  for (int k = 0; k < wid; k++) woff += wsm[k];
  if (t < Bs) part[t] = woff + s - v;
  if (t == 0) rowptr[N] = wsm[0] + wsm[1] + wsm[2] + wsm[3];
}

// writes exclusive prefix to rowptr AND cur (cur = scatter write cursor)
__global__ __launch_bounds__(256) void scanC(const int* __restrict__ cnt,
                                             const int* __restrict__ part,
                                             int* __restrict__ rowptr, int* __restrict__ cur,
                                             int N) {
  int i = blockIdx.x * 256 + threadIdx.x;
  int v = (i < N) ? cnt[i] : 0;
  int lane = threadIdx.x & 63, wid = threadIdx.x >> 6;
  int s = v;
#pragma unroll
  for (int o = 1; o < 64; o <<= 1) {
    int u = __shfl_up(s, o);
    if (lane >= o) s += u;
  }
  __shared__ int wsm[4];
  if (lane == 63) wsm[wid] = s;
  __syncthreads();
  int woff = 0;
  for (int k = 0; k < wid; k++) woff += wsm[k];
  if (i < N) {
    int val = part[blockIdx.x] + woff + s - v;
    rowptr[i] = val;
    cur[i] = val;
  }
}

// ---------------- scatter, XCD-partitioned by dst range; cur pre-seeded with rowptr --------
__global__ __launch_bounds__(256) void scatter_part(const int* __restrict__ ei,
                                                    int* __restrict__ cur, int* __restrict__ adj,
                                                    int E, int ET, int Nper) {
  int part = blockIdx.x & 7;
  int t = (blockIdx.x >> 3) * 256 + threadIdx.x;
  if (t >= ET) return;
  int dst = (t < E) ? ei[E + t] : (t - E);
  if ((unsigned)(dst - part * Nper) < (unsigned)Nper) {
    int src = (t < E) ? ei[t] : dst;
    int pos = atomicAdd(&cur[dst], 1);
    adj[pos] = src;
  }
}

// ---------------- proj2 via MFMA (swapped operands, no LDS, 1 Mtile/wave) ----------------
template <typename TIN, int DOUT>
__global__ __launch_bounds__(256) void proj_mfma(const TIN* __restrict__ X,
                                                 const unsigned short* __restrict__ wsrc,
                                                 const float* __restrict__ Ba,
                                                 const float* __restrict__ Bb,
                                                 _Float16* __restrict__ Ya,
                                                 _Float16* __restrict__ Yb, int Mtiles) {
  constexpr int NPM = DOUT / 16;
  constexpr unsigned MATB = DOUT * 256;
  const int t = threadIdx.x;
  const int l = t & 63, wv = t >> 6;
  const int mt = blockIdx.x * 4 + wv;
  if (mt >= Mtiles) return;
  const int r15 = l & 15, kq = l >> 4;

  bf16x8 a0[4];
  {
    const TIN* px = X + ((size_t)(mt * 16 + r15)) * 128 + kq * 8;
#pragma unroll
    for (int ks = 0; ks < 4; ++ks) a0[ks] = load_frag(px + ks * 32);
  }

  for (int nt = 0; nt < 2 * NPM; ++nt) {
    const int mat = nt / NPM;
    const int o = (nt % NPM) * 16 + r15;
    bf16x8 b[4];
#pragma unroll
    for (int ks = 0; ks < 4; ++ks) {
      unsigned byteoff =
          (((unsigned)(o * 256 + (ks * 32 + kq * 8) * 2)) ^ ((unsigned)(o & 7) << 4)) +
          (unsigned)mat * MATB;
      b[ks] = *(const bf16x8*)((const char*)wsrc + byteoff);
    }
    f32x4 c0 = {0.f, 0.f, 0.f, 0.f};
#pragma unroll
    for (int ks = 0; ks < 4; ++ks)
      c0 = __builtin_amdgcn_mfma_f32_16x16x32_bf16(b[ks], a0[ks], c0, 0, 0, 0);
    _Float16* Y = mat ? Yb : Ya;
    const float* Bv = mat ? Bb : Ba;
    const int obase = (nt % NPM) * 16 + 4 * kq;
    float4 b4 = *(const float4*)(Bv + obase);
    union { f16x2 h[2]; uint2 u; } pk;
    pk.h[0] = pkrtz(c0[0] + b4.x, c0[1] + b4.y);
    pk.h[1] = pkrtz(c0[2] + b4.z, c0[3] + b4.w);
    *(uint2*)(Y + (size_t)(mt * 16 + r15) * DOUT + obase) = pk.u;
  }
}

// ---------------- fused GAT layer 1: wave/dst, 4 streams x 16 lanes, 8ch/lane --------------
// head = sub>>2; per-head logit = xor1+xor2 over subs {4h..4h+3} = ch [32h,32h+32).
__global__ __launch_bounds__(256) void gat1(const _Float16* __restrict__ xl,
                                            const _Float16* __restrict__ xr,
                                            unsigned short* __restrict__ h_out,
                                            const int* __restrict__ rowptr,
                                            const int* __restrict__ adj,
                                            const float* __restrict__ att,
                                            const float* __restrict__ bias,
                                            const float* __restrict__ g,
                                            const float* __restrict__ be, int N) {
  int w = blockIdx.x * 4 + (threadIdx.x >> 6);
  int l = threadIdx.x & 63;
  if (w >= N) return;
  int sub = l & 15, strm = l >> 4;
  f16x8 xr8 = *(const f16x8*)(xr + (size_t)w * 128 + 8 * sub);
  const f16x2* xr2 = (const f16x2*)&xr8;
  f16x2 at2[4];
#pragma unroll
  for (int q = 0; q < 4; ++q) {
    at2[q][0] = (_Float16)att[8 * sub + 2 * q];
    at2[q][1] = (_Float16)att[8 * sub + 2 * q + 1];
  }
  float den = 0.f;
  float acc[8] = {0.f, 0.f, 0.f, 0.f, 0.f, 0.f, 0.f, 0.f};
  int j0 = rowptr[w], j1 = rowptr[w + 1];

  auto proc = [&](f16x8 a8) {
    const f16x2* a2 = (const f16x2*)&a8;
    float s = 0.f;
#pragma unroll
    for (int q = 0; q < 4; ++q) {
      f16x2 e = a2[q] + xr2[q];
      e = __builtin_elementwise_max(e, e * (_Float16)0.2f);
      s = __builtin_amdgcn_fdot2(e, at2[q], s, false);
    }
    s = dpp_add<0xB1>(s);  // xor1
    s = dpp_add<0x4E>(s);  // xor2 -> full 32-ch head logit
    float p = __expf(s);   // shift-invariant: no max subtraction needed in f32
    den += p;
#pragma unroll
    for (int c = 0; c < 8; ++c) acc[c] = fmaf((float)a8[c], p, acc[c]);  // v_fma_mix
  };

  int j = j0 + strm;
  if (j < j1) {
    f16x8 a = *(const f16x8*)(xl + (size_t)adj[j] * 128 + 8 * sub);
    for (j += 4; j < j1; j += 4) {
      f16x8 an = *(const f16x8*)(xl + (size_t)adj[j] * 128 + 8 * sub);
      proc(a);
      a = an;
    }
    proc(a);
  }

  // merge 4 streams: plain sums (shared implicit offset)
  den = swz_add<0x401F>(den);
#pragma unroll
  for (int c = 0; c < 8; ++c) acc[c] = swz_add<0x401F>(acc[c]);
  den += __shfl_xor(den, 32);
#pragma unroll
  for (int c = 0; c < 8; ++c) acc[c] += __shfl_xor(acc[c], 32);

  float inv = 1.f / (den + 1e-16f);
  float v[8], s1 = 0.f, s2 = 0.f;
#pragma unroll
  for (int c = 0; c < 8; ++c) {
    v[c] = fmaf(acc[c], inv, bias[8 * sub + c]);
    s1 += v[c];
    s2 = fmaf(v[c], v[c], s2);
  }
  s1 = dpp_add<0xB1>(s1); s2 = dpp_add<0xB1>(s2);
  s1 = dpp_add<0x4E>(s1); s2 = dpp_add<0x4E>(s2);
  s1 = swz_add<0x101F>(s1); s2 = swz_add<0x101F>(s2);  // xor4
  s1 = swz_add<0x201F>(s1); s2 = swz_add<0x201F>(s2);  // xor8
  float mu = s1 * (1.f / 128.f);
  float var = s2 * (1.f / 128.f) - mu * mu;
  float rs = rsqrtf(var + 1e-5f);
  if (strm == 0) {
    unsigned short o8[8];
#pragma unroll
    for (int c = 0; c < 8; ++c) {
      float r = (v[c] - mu) * rs * g[8 * sub + c] + be[8 * sub + c];
      r = r > 0.f ? r : __expf(r) - 1.f;  // ELU
      o8[c] = f2bf(r);
    }
    *(uint4*)(h_out + (size_t)w * 128 + 8 * sub) = *(const uint4*)o8;
  }
}

// ---------------- fused GAT layer 2: wave/dst, 8 streams x 8 lanes, 8ch/lane ---------------
__global__ __launch_bounds__(256) void gat2(const _Float16* __restrict__ hl,
                                            const _Float16* __restrict__ hr,
                                            const int* __restrict__ rowptr,
                                            const int* __restrict__ adj,
                                            const float* __restrict__ att,
                                            const float* __restrict__ bias,
                                            const float* __restrict__ g,
                                            const float* __restrict__ be,
                                            _Float16* __restrict__ z, int N) {
  int w = blockIdx.x * 4 + (threadIdx.x >> 6);
  int l = threadIdx.x & 63;
  if (w >= N) return;
  int sub = l & 7, strm = l >> 3;
  f16x8 xr8 = *(const f16x8*)(hr + (size_t)w * 64 + 8 * sub);
  const f16x2* xr2 = (const f16x2*)&xr8;
  f16x2 at2[4];
#pragma unroll
  for (int q = 0; q < 4; ++q) {
    at2[q][0] = (_Float16)att[8 * sub + 2 * q];
    at2[q][1] = (_Float16)att[8 * sub + 2 * q + 1];
  }
  float den = 0.f;
  float acc[8] = {0.f, 0.f, 0.f, 0.f, 0.f, 0.f, 0.f, 0.f};
  int j0 = rowptr[w], j1 = rowptr[w + 1];

  auto proc = [&](f16x8 a8) {
    const f16x2* a2 = (const f16x2*)&a8;
    float s = 0.f;
#pragma unroll
    for (int q = 0; q < 4; ++q) {
      f16x2 e = a2[q] + xr2[q];
      e = __builtin_elementwise_max(e, e * (_Float16)0.2f);
      s = __builtin_amdgcn_fdot2(e, at2[q], s, false);
    }
    s = dpp_add<0xB1>(s);
    s = dpp_add<0x4E>(s);
    s = swz_add<0x101F>(s);  // xor4 -> full 64-ch (single-head) logit
    float p = __expf(s);
    den += p;
#pragma unroll
    for (int c = 0; c < 8; ++c) acc[c] = fmaf((float)a8[c], p, acc[c]);
  };

  int j = j0 + strm;
  if (j < j1) {
    f16x8 a = *(const f16x8*)(hl + (size_t)adj[j] * 64 + 8 * sub);
    for (j += 8; j < j1; j += 8) {
      f16x8 an = *(const f16x8*)(hl + (size_t)adj[j] * 64 + 8 * sub);
      proc(a);
      a = an;
    }
    proc(a);
  }

  den = swz_add<0x201F>(den);
#pragma unroll
  for (int c = 0; c < 8; ++c) acc[c] = swz_add<0x201F>(acc[c]);
  den = swz_add<0x401F>(den);
#pragma unroll
  for (int c = 0; c < 8; ++c) acc[c] = swz_add<0x401F>(acc[c]);
  den += __shfl_xor(den, 32);
#pragma unroll
  for (int c = 0; c < 8; ++c) acc[c] += __shfl_xor(acc[c], 32);

  float inv = 1.f / (den + 1e-16f);
  float v[8], s1 = 0.f, s2 = 0.f;
#pragma unroll
  for (int c = 0; c < 8; ++c) {
    v[c] = fmaf(acc[c], inv, bias[8 * sub + c]);
    s1 += v[c];
    s2 = fmaf(v[c], v[c], s2);
  }
  s1 = dpp_add<0xB1>(s1); s2 = dpp_add<0xB1>(s2);
  s1 = dpp_add<0x4E>(s1); s2 = dpp_add<0x4E>(s2);
  s1 = swz_add<0x101F>(s1); s2 = swz_add<0x101F>(s2);
  float mu = s1 * (1.f / 64.f);
  float var = s2 * (1.f / 64.f) - mu * mu;
  float rs = rsqrtf(var + 1e-5f);
  if (strm == 0) {
    f16x8 zz;
#pragma unroll
    for (int c = 0; c < 8; ++c)
      zz[c] = (_Float16)((v[c] - mu) * rs * g[8 * sub + c] + be[8 * sub + c]);
    *(f16x8*)(z + (size_t)w * 64 + 8 * sub) = zz;
  }
}

// ---------------- decode: 8 pairs per wave, 8 lanes per pair, fdot2 ----------------
__global__ __launch_bounds__(256) void decode(const _Float16* __restrict__ z,
                                              const int* __restrict__ eli,
                                              float* __restrict__ out, int EL) {
  int wv = threadIdx.x >> 6, l = threadIdx.x & 63;
  int sub = l & 7;
  int pidx = (blockIdx.x * 4 + wv) * 8 + (l >> 3);
  if (pidx >= EL) return;
  int a = eli[pidx], b = eli[EL + pidx];
  f16x8 za = *(const f16x8*)(z + (size_t)a * 64 + 8 * sub);
  f16x8 zb = *(const f16x8*)(z + (size_t)b * 64 + 8 * sub);
  const f16x2* za2 = (const f16x2*)&za;
  const f16x2* zb2 = (const f16x2*)&zb;
  float p = 0.f;
#pragma unroll
  for (int q = 0; q < 4; ++q) p = __builtin_amdgcn_fdot2(za2[q], zb2[q], p, false);
  p = dpp_add<0xB1>(p);
  p = dpp_add<0x4E>(p);
  p = swz_add<0x101F>(p);
  if (sub == 0) out[pidx] = p;
}

extern "C" void kernel_launch(void* const* d_in, const int* in_sizes, int n_in, void* d_out,
                              int out_size, void* d_ws, size_t ws_size, hipStream_t stream) {
  const float* x = (const float*)d_in[0];
  const int* ei = (const int*)d_in[1];
  const int* eli = (const int*)d_in[2];
  const float* W1l = (const float*)d_in[3];
  const float* b1l = (const float*)d_in[4];
  const float* W1r = (const float*)d_in[5];
  const float* b1r = (const float*)d_in[6];
  const float* att1 = (const float*)d_in[7];
  const float* bias1 = (const float*)d_in[8];
  const float* g1 = (const float*)d_in[9];
  const float* be1 = (const float*)d_in[10];
  const float* W2l = (const float*)d_in[11];
  const float* b2l = (const float*)d_in[12];
  const float* W2r = (const float*)d_in[13];
  const float* b2r = (const float*)d_in[14];
  const float* att2 = (const float*)d_in[15];
  const float* bias2 = (const float*)d_in[16];
  const float* g2 = (const float*)d_in[17];
  const float* be2 = (const float*)d_in[18];

  const int N = in_sizes[0] / 128;
  const int E = in_sizes[1] / 2;
  const int EL = in_sizes[2] / 2;
  const int ET = E + N;

  char* base = (char*)d_ws;
  _Float16* xl16 = (_Float16*)base;                                  // N*128 f16
  _Float16* xr16 = (_Float16*)(base + (size_t)N * 256);              // N*128 f16
  unsigned short* h_bf = (unsigned short*)(base + (size_t)N * 512);  // N*128 bf16
  _Float16* hl16 = (_Float16*)(base + (size_t)N * 768);              // N*64 f16
  _Float16* hr16 = (_Float16*)(base + (size_t)N * 896);              // N*64 f16
  _Float16* z16 = (_Float16*)(base + (size_t)N * 1024);              // N*64 f16
  int* ib = (int*)(base + (size_t)N * 1152);
  int* cnt = ib;
  int* cur = ib + N;
  int* rowptr = ib + 2 * N;
  int* part = ib + 3 * N + 2;
  int* adj = ib + 3 * N + 258;
  size_t ints_bytes = ((size_t)(3 * N + 258) + (size_t)ET) * 4;
  unsigned short* wbuf =
      (unsigned short*)(base + (((size_t)N * 1152 + ints_bytes + 255) & ~(size_t)255));

  const int n4 = (N + 3) / 4;
  prep0<<<64, 256, 0, stream>>>(W1l, W1r, W2l, W2r, wbuf, (int4*)cnt, n4);

  const int eB = (ET + 255) / 256;
  const int Mtiles = (N + 15) / 16;
  const int pBlocks = (Mtiles + 3) / 4;
  projdeg<<<pBlocks + eB, 256, 0, stream>>>(x, wbuf, b1l, b1r, xl16, xr16, Mtiles, pBlocks, ei,
                                            cnt, E, ET);

  const int nB = (N + 255) / 256;
  scanA<<<nB, 256, 0, stream>>>(cnt, part, N);
  scanB<<<1, 256, 0, stream>>>(part, rowptr, nB, N);
  scanC<<<nB, 256, 0, stream>>>(cnt, part, rowptr, cur, N);

  const int Nper = (N + 7) / 8;
  scatter_part<<<8 * eB, 256, 0, stream>>>(ei, cur, adj, E, ET, Nper);

  const int gB = (N + 3) / 4;
  gat1<<<gB, 256, 0, stream>>>(xl16, xr16, h_bf, rowptr, adj, att1, bias1, g1, be1, N);

  proj_mfma<unsigned short, 64>
      <<<pBlocks, 256, 0, stream>>>(h_bf, wbuf + 32768, b2l, b2r, hl16, hr16, Mtiles);

  gat2<<<gB, 256, 0, stream>>>(hl16, hr16, rowptr, adj, att2, bias2, g2, be2, z16, N);

  const int dBlocks = (EL + 31) / 32;
  decode<<<dBlocks, 256, 0, stream>>>(z16, eli, (float*)d_out, EL);
}

// Round 19
// 183.155 us; speedup vs baseline: 1.0242x; 1.0242x over previous
//
#include <hip/hip_runtime.h>
#include <hip/hip_bf16.h>

// GATv2 link predictor: N=50000, E=800000 (+N self loops), IN=128, HID=32, HEADS=4, OUT=64
// f32 in/out. CSR + fused GAT layers, shift-invariant softmax, pk-f16 logit math, f32 accum.
// bf16 MFMA projections (swapped operand, pre-swizzled W image).
// Round 19: degree-count inside projdeg is XCD-PARTITIONED (r18 showed projdeg's 52us was
// invariant to occupancy/LDS/VGPR => critical path = 850k cross-XCD atomics on 200KB cnt,
// same thrash scatter had; WRITE_SIZE 50MB for 25.6MB of payload). proj2 keeps LDS staging.

#define DEVFN __device__ __forceinline__

typedef __attribute__((ext_vector_type(4))) float f32x4;
typedef __attribute__((ext_vector_type(8))) short bf16x8;
typedef _Float16 f16x2 __attribute__((ext_vector_type(2)));
typedef _Float16 f16x8 __attribute__((ext_vector_type(8)));

DEVFN unsigned short f2bf(float f) {  // RNE f32->bf16
  unsigned u = __float_as_uint(f);
  return (unsigned short)((u + 0x7fffu + ((u >> 16) & 1u)) >> 16);
}

DEVFN f16x2 pkrtz(float a, float b) {
  auto r = __builtin_amdgcn_cvt_pkrtz(a, b);
  union { decltype(r) s; f16x2 d; } u;
  u.s = r;
  return u.d;
}

template <int CTRL>
DEVFN float dpp_add(float s) {
  int x = __builtin_amdgcn_update_dpp(0, __float_as_int(s), CTRL, 0xF, 0xF, true);
  return s + __int_as_float(x);
}
template <int OFF>
DEVFN float swz_add(float s) {
  int x = __builtin_amdgcn_ds_swizzle(__float_as_int(s), OFF);
  return s + __int_as_float(x);
}

DEVFN bf16x8 load_frag(const float* p) {
  f32x4 u = *(const f32x4*)p;
  f32x4 v = *(const f32x4*)(p + 4);
  union { unsigned r[4]; bf16x8 h; } o;
  asm("v_cvt_pk_bf16_f32 %0, %1, %2" : "=v"(o.r[0]) : "v"(u[0]), "v"(u[1]));
  asm("v_cvt_pk_bf16_f32 %0, %1, %2" : "=v"(o.r[1]) : "v"(u[2]), "v"(u[3]));
  asm("v_cvt_pk_bf16_f32 %0, %1, %2" : "=v"(o.r[2]) : "v"(v[0]), "v"(v[1]));
  asm("v_cvt_pk_bf16_f32 %0, %1, %2" : "=v"(o.r[3]) : "v"(v[2]), "v"(v[3]));
  return o.h;
}
DEVFN bf16x8 load_frag(const unsigned short* p) { return *(const bf16x8*)p; }

// ---------------- prep0: W->bf16 swizzled image + zero cnt ----------------
__global__ __launch_bounds__(256) void prep0(const float* __restrict__ W1l,
                                             const float* __restrict__ W1r,
                                             const float* __restrict__ W2l,
                                             const float* __restrict__ W2r,
                                             unsigned short* __restrict__ wbuf,
                                             int4* __restrict__ cnt4, int n4) {
  int t = blockIdx.x * 256 + threadIdx.x;
  if (t < 16384) {  // W1: [128][128]
    int k = t >> 7, o = t & 127;
    unsigned off = ((unsigned)(o * 256 + k * 2)) ^ ((unsigned)(o & 7) << 4);
    wbuf[off >> 1] = f2bf(W1l[t]);
    wbuf[16384 + (off >> 1)] = f2bf(W1r[t]);
  }
  if (t < 8192) {  // W2: [128][64]
    int k = t >> 6, o = t & 63;
    unsigned off = ((unsigned)(o * 256 + k * 2)) ^ ((unsigned)(o & 7) << 4);
    wbuf[32768 + (off >> 1)] = f2bf(W2l[t]);
    wbuf[40960 + (off >> 1)] = f2bf(W2r[t]);
  }
  if (t < n4) cnt4[t] = make_int4(0, 0, 0, 0);
}

// ---------------- projdeg: proj1 (MFMA, no LDS) + XCD-partitioned degree count -------------
// blocks [0,pBlocks): projection. blocks [pBlocks, pBlocks+8*eB): degree count, where
// block d = idx-pBlocks handles dst partition d&7 only (cnt lines stay in one XCD's L2).
__global__ __launch_bounds__(256) void projdeg(const float* __restrict__ X,
                                               const unsigned short* __restrict__ wsrc,
                                               const float* __restrict__ Ba,
                                               const float* __restrict__ Bb,
                                               _Float16* __restrict__ Ya,
                                               _Float16* __restrict__ Yb, int Mtiles, int pBlocks,
                                               const int* __restrict__ ei, int* __restrict__ cnt,
                                               int E, int ET, int Nper) {
  constexpr int DOUT = 128;
  constexpr int NPM = DOUT / 16;
  constexpr unsigned MATB = DOUT * 256;
  if (blockIdx.x >= pBlocks) {  // degree-count blocks, XCD-partitioned
    int d = blockIdx.x - pBlocks;
    int part = d & 7;
    int t = (d >> 3) * 256 + threadIdx.x;
    if (t < ET) {
      int dst = (t < E) ? ei[E + t] : (t - E);
      if ((unsigned)(dst - part * Nper) < (unsigned)Nper) atomicAdd(&cnt[dst], 1);
    }
    return;
  }
  const int t = threadIdx.x;
  const int l = t & 63, wv = t >> 6;
  const int mt = blockIdx.x * 4 + wv;
  if (mt >= Mtiles) return;
  const int r15 = l & 15, kq = l >> 4;

  bf16x8 a0[4];
  {
    const float* px = X + ((size_t)(mt * 16 + r15)) * 128 + kq * 8;
#pragma unroll
    for (int ks = 0; ks < 4; ++ks) a0[ks] = load_frag(px + ks * 32);
  }

  for (int nt = 0; nt < 2 * NPM; ++nt) {
    const int mat = nt / NPM;
    const int o = (nt % NPM) * 16 + r15;
    bf16x8 b[4];
#pragma unroll
    for (int ks = 0; ks < 4; ++ks) {
      unsigned byteoff =
          (((unsigned)(o * 256 + (ks * 32 + kq * 8) * 2)) ^ ((unsigned)(o & 7) << 4)) +
          (unsigned)mat * MATB;
      b[ks] = *(const bf16x8*)((const char*)wsrc + byteoff);  // L2-hot 64KB image
    }
    f32x4 c0 = {0.f, 0.f, 0.f, 0.f};
#pragma unroll
    for (int ks = 0; ks < 4; ++ks)
      c0 = __builtin_amdgcn_mfma_f32_16x16x32_bf16(b[ks], a0[ks], c0, 0, 0, 0);
    _Float16* Y = mat ? Yb : Ya;
    const float* Bv = mat ? Bb : Ba;
    const int obase = (nt % NPM) * 16 + 4 * kq;
    float4 b4 = *(const float4*)(Bv + obase);
    union { f16x2 h[2]; uint2 u; } pk;
    pk.h[0] = pkrtz(c0[0] + b4.x, c0[1] + b4.y);
    pk.h[1] = pkrtz(c0[2] + b4.z, c0[3] + b4.w);
    *(uint2*)(Y + (size_t)(mt * 16 + r15) * DOUT + obase) = pk.u;
  }
}

// ---------------- CSR scan: 3-kernel parallel version ----------------
__global__ __launch_bounds__(256) void scanA(const int* __restrict__ cnt, int* __restrict__ part,
                                             int N) {
  int i = blockIdx.x * 256 + threadIdx.x;
  int v = (i < N) ? cnt[i] : 0;
  __shared__ int wsm[4];
  int lane = threadIdx.x & 63, wid = threadIdx.x >> 6;
#pragma unroll
  for (int o = 1; o < 64; o <<= 1) v += __shfl_xor(v, o);
  if (lane == 0) wsm[wid] = v;
  __syncthreads();
  if (threadIdx.x == 0) part[blockIdx.x] = wsm[0] + wsm[1] + wsm[2] + wsm[3];
}

__global__ __launch_bounds__(256) void scanB(int* __restrict__ part, int* __restrict__ rowptr,
                                             int Bs, int N) {
  int t = threadIdx.x;
  int v = (t < Bs) ? part[t] : 0;
  int lane = t & 63, wid = t >> 6;
  int s = v;
#pragma unroll
  for (int o = 1; o < 64; o <<= 1) {
    int u = __shfl_up(s, o);
    if (lane >= o) s += u;
  }
  __shared__ int wsm[4];
  if (lane == 63) wsm[wid] = s;
  __syncthreads();
  int woff = 0;
  for (int k = 0; k < wid; k++) woff += wsm[k];
  if (t < Bs) part[t] = woff + s - v;
  if (t == 0) rowptr[N] = wsm[0] + wsm[1] + wsm[2] + wsm[3];
}

// writes exclusive prefix to rowptr AND cur (cur = scatter write cursor)
__global__ __launch_bounds__(256) void scanC(const int* __restrict__ cnt,
                                             const int* __restrict__ part,
                                             int* __restrict__ rowptr, int* __restrict__ cur,
                                             int N) {
  int i = blockIdx.x * 256 + threadIdx.x;
  int v = (i < N) ? cnt[i] : 0;
  int lane = threadIdx.x & 63, wid = threadIdx.x >> 6;
  int s = v;
#pragma unroll
  for (int o = 1; o < 64; o <<= 1) {
    int u = __shfl_up(s, o);
    if (lane >= o) s += u;
  }
  __shared__ int wsm[4];
  if (lane == 63) wsm[wid] = s;
  __syncthreads();
  int woff = 0;
  for (int k = 0; k < wid; k++) woff += wsm[k];
  if (i < N) {
    int val = part[blockIdx.x] + woff + s - v;
    rowptr[i] = val;
    cur[i] = val;
  }
}

// ---------------- scatter, XCD-partitioned by dst range; cur pre-seeded with rowptr --------
__global__ __launch_bounds__(256) void scatter_part(const int* __restrict__ ei,
                                                    int* __restrict__ cur, int* __restrict__ adj,
                                                    int E, int ET, int Nper) {
  int part = blockIdx.x & 7;
  int t = (blockIdx.x >> 3) * 256 + threadIdx.x;
  if (t >= ET) return;
  int dst = (t < E) ? ei[E + t] : (t - E);
  if ((unsigned)(dst - part * Nper) < (unsigned)Nper) {
    int src = (t < E) ? ei[t] : dst;
    int pos = atomicAdd(&cur[dst], 1);
    adj[pos] = src;
  }
}

// ---------------- proj2 via MFMA (swapped operands, LDS-staged W image) ----------------
template <typename TIN, int DOUT>
__global__ __launch_bounds__(256) void proj_mfma(const TIN* __restrict__ X,
                                                 const unsigned short* __restrict__ wsrc,
                                                 const float* __restrict__ Ba,
                                                 const float* __restrict__ Bb,
                                                 _Float16* __restrict__ Ya,
                                                 _Float16* __restrict__ Yb, int Mtiles) {
  constexpr int NPM = DOUT / 16;
  constexpr unsigned MATB = DOUT * 256;
  __shared__ unsigned short sW[2 * DOUT * 128];
  const int t = threadIdx.x;
  {
    const char* gsrc = (const char*)wsrc;
    char* lds = (char*)sW;
    for (unsigned off = t * 16; off < 2 * MATB; off += 256 * 16)
      *(uint4*)(lds + off) = *(const uint4*)(gsrc + off);
  }
  __syncthreads();
  const int l = t & 63, wv = t >> 6;
  const int mt = blockIdx.x * 4 + wv;
  if (mt >= Mtiles) return;
  const int r15 = l & 15, kq = l >> 4;

  bf16x8 a0[4];
  {
    const TIN* px = X + ((size_t)(mt * 16 + r15)) * 128 + kq * 8;
#pragma unroll
    for (int ks = 0; ks < 4; ++ks) a0[ks] = load_frag(px + ks * 32);
  }

  for (int nt = 0; nt < 2 * NPM; ++nt) {
    const int mat = nt / NPM;
    const int o = (nt % NPM) * 16 + r15;
    bf16x8 b[4];
#pragma unroll
    for (int ks = 0; ks < 4; ++ks) {
      unsigned byteoff =
          (((unsigned)(o * 256 + (ks * 32 + kq * 8) * 2)) ^ ((unsigned)(o & 7) << 4)) +
          (unsigned)mat * MATB;
      b[ks] = *(const bf16x8*)((const char*)sW + byteoff);
    }
    f32x4 c0 = {0.f, 0.f, 0.f, 0.f};
#pragma unroll
    for (int ks = 0; ks < 4; ++ks)
      c0 = __builtin_amdgcn_mfma_f32_16x16x32_bf16(b[ks], a0[ks], c0, 0, 0, 0);
    _Float16* Y = mat ? Yb : Ya;
    const float* Bv = mat ? Bb : Ba;
    const int obase = (nt % NPM) * 16 + 4 * kq;
    float4 b4 = *(const float4*)(Bv + obase);
    union { f16x2 h[2]; uint2 u; } pk;
    pk.h[0] = pkrtz(c0[0] + b4.x, c0[1] + b4.y);
    pk.h[1] = pkrtz(c0[2] + b4.z, c0[3] + b4.w);
    *(uint2*)(Y + (size_t)(mt * 16 + r15) * DOUT + obase) = pk.u;
  }
}

// ---------------- fused GAT layer 1: wave/dst, 4 streams x 16 lanes, 8ch/lane --------------
// head = sub>>2; per-head logit = xor1+xor2 over subs {4h..4h+3} = ch [32h,32h+32).
__global__ __launch_bounds__(256) void gat1(const _Float16* __restrict__ xl,
                                            const _Float16* __restrict__ xr,
                                            unsigned short* __restrict__ h_out,
                                            const int* __restrict__ rowptr,
                                            const int* __restrict__ adj,
                                            const float* __restrict__ att,
                                            const float* __restrict__ bias,
                                            const float* __restrict__ g,
                                            const float* __restrict__ be, int N) {
  int w = blockIdx.x * 4 + (threadIdx.x >> 6);
  int l = threadIdx.x & 63;
  if (w >= N) return;
  int sub = l & 15, strm = l >> 4;
  f16x8 xr8 = *(const f16x8*)(xr + (size_t)w * 128 + 8 * sub);
  const f16x2* xr2 = (const f16x2*)&xr8;
  f16x2 at2[4];
#pragma unroll
  for (int q = 0; q < 4; ++q) {
    at2[q][0] = (_Float16)att[8 * sub + 2 * q];
    at2[q][1] = (_Float16)att[8 * sub + 2 * q + 1];
  }
  float den = 0.f;
  float acc[8] = {0.f, 0.f, 0.f, 0.f, 0.f, 0.f, 0.f, 0.f};
  int j0 = rowptr[w], j1 = rowptr[w + 1];

  auto proc = [&](f16x8 a8) {
    const f16x2* a2 = (const f16x2*)&a8;
    float s = 0.f;
#pragma unroll
    for (int q = 0; q < 4; ++q) {
      f16x2 e = a2[q] + xr2[q];
      e = __builtin_elementwise_max(e, e * (_Float16)0.2f);
      s = __builtin_amdgcn_fdot2(e, at2[q], s, false);
    }
    s = dpp_add<0xB1>(s);  // xor1
    s = dpp_add<0x4E>(s);  // xor2 -> full 32-ch head logit
    float p = __expf(s);   // shift-invariant: no max subtraction needed in f32
    den += p;
#pragma unroll
    for (int c = 0; c < 8; ++c) acc[c] = fmaf((float)a8[c], p, acc[c]);  // v_fma_mix
  };

  int j = j0 + strm;
  if (j < j1) {
    f16x8 a = *(const f16x8*)(xl + (size_t)adj[j] * 128 + 8 * sub);
    for (j += 4; j < j1; j += 4) {
      f16x8 an = *(const f16x8*)(xl + (size_t)adj[j] * 128 + 8 * sub);
      proc(a);
      a = an;
    }
    proc(a);
  }

  // merge 4 streams: plain sums (shared implicit offset)
  den = swz_add<0x401F>(den);
#pragma unroll
  for (int c = 0; c < 8; ++c) acc[c] = swz_add<0x401F>(acc[c]);
  den += __shfl_xor(den, 32);
#pragma unroll
  for (int c = 0; c < 8; ++c) acc[c] += __shfl_xor(acc[c], 32);

  float inv = 1.f / (den + 1e-16f);
  float v[8], s1 = 0.f, s2 = 0.f;
#pragma unroll
  for (int c = 0; c < 8; ++c) {
    v[c] = fmaf(acc[c], inv, bias[8 * sub + c]);
    s1 += v[c];
    s2 = fmaf(v[c], v[c], s2);
  }
  s1 = dpp_add<0xB1>(s1); s2 = dpp_add<0xB1>(s2);
  s1 = dpp_add<0x4E>(s1); s2 = dpp_add<0x4E>(s2);
  s1 = swz_add<0x101F>(s1); s2 = swz_add<0x101F>(s2);  // xor4
  s1 = swz_add<0x201F>(s1); s2 = swz_add<0x201F>(s2);  // xor8
  float mu = s1 * (1.f / 128.f);
  float var = s2 * (1.f / 128.f) - mu * mu;
  float rs = rsqrtf(var + 1e-5f);
  if (strm == 0) {
    unsigned short o8[8];
#pragma unroll
    for (int c = 0; c < 8; ++c) {
      float r = (v[c] - mu) * rs * g[8 * sub + c] + be[8 * sub + c];
      r = r > 0.f ? r : __expf(r) - 1.f;  // ELU
      o8[c] = f2bf(r);
    }
    *(uint4*)(h_out + (size_t)w * 128 + 8 * sub) = *(const uint4*)o8;
  }
}

// ---------------- fused GAT layer 2: wave/dst, 8 streams x 8 lanes, 8ch/lane ---------------
__global__ __launch_bounds__(256) void gat2(const _Float16* __restrict__ hl,
                                            const _Float16* __restrict__ hr,
                                            const int* __restrict__ rowptr,
                                            const int* __restrict__ adj,
                                            const float* __restrict__ att,
                                            const float* __restrict__ bias,
                                            const float* __restrict__ g,
                                            const float* __restrict__ be,
                                            _Float16* __restrict__ z, int N) {
  int w = blockIdx.x * 4 + (threadIdx.x >> 6);
  int l = threadIdx.x & 63;
  if (w >= N) return;
  int sub = l & 7, strm = l >> 3;
  f16x8 xr8 = *(const f16x8*)(hr + (size_t)w * 64 + 8 * sub);
  const f16x2* xr2 = (const f16x2*)&xr8;
  f16x2 at2[4];
#pragma unroll
  for (int q = 0; q < 4; ++q) {
    at2[q][0] = (_Float16)att[8 * sub + 2 * q];
    at2[q][1] = (_Float16)att[8 * sub + 2 * q + 1];
  }
  float den = 0.f;
  float acc[8] = {0.f, 0.f, 0.f, 0.f, 0.f, 0.f, 0.f, 0.f};
  int j0 = rowptr[w], j1 = rowptr[w + 1];

  auto proc = [&](f16x8 a8) {
    const f16x2* a2 = (const f16x2*)&a8;
    float s = 0.f;
#pragma unroll
    for (int q = 0; q < 4; ++q) {
      f16x2 e = a2[q] + xr2[q];
      e = __builtin_elementwise_max(e, e * (_Float16)0.2f);
      s = __builtin_amdgcn_fdot2(e, at2[q], s, false);
    }
    s = dpp_add<0xB1>(s);
    s = dpp_add<0x4E>(s);
    s = swz_add<0x101F>(s);  // xor4 -> full 64-ch (single-head) logit
    float p = __expf(s);
    den += p;
#pragma unroll
    for (int c = 0; c < 8; ++c) acc[c] = fmaf((float)a8[c], p, acc[c]);
  };

  int j = j0 + strm;
  if (j < j1) {
    f16x8 a = *(const f16x8*)(hl + (size_t)adj[j] * 64 + 8 * sub);
    for (j += 8; j < j1; j += 8) {
      f16x8 an = *(const f16x8*)(hl + (size_t)adj[j] * 64 + 8 * sub);
      proc(a);
      a = an;
    }
    proc(a);
  }

  den = swz_add<0x201F>(den);
#pragma unroll
  for (int c = 0; c < 8; ++c) acc[c] = swz_add<0x201F>(acc[c]);
  den = swz_add<0x401F>(den);
#pragma unroll
  for (int c = 0; c < 8; ++c) acc[c] = swz_add<0x401F>(acc[c]);
  den += __shfl_xor(den, 32);
#pragma unroll
  for (int c = 0; c < 8; ++c) acc[c] += __shfl_xor(acc[c], 32);

  float inv = 1.f / (den + 1e-16f);
  float v[8], s1 = 0.f, s2 = 0.f;
#pragma unroll
  for (int c = 0; c < 8; ++c) {
    v[c] = fmaf(acc[c], inv, bias[8 * sub + c]);
    s1 += v[c];
    s2 = fmaf(v[c], v[c], s2);
  }
  s1 = dpp_add<0xB1>(s1); s2 = dpp_add<0xB1>(s2);
  s1 = dpp_add<0x4E>(s1); s2 = dpp_add<0x4E>(s2);
  s1 = swz_add<0x101F>(s1); s2 = swz_add<0x101F>(s2);
  float mu = s1 * (1.f / 64.f);
  float var = s2 * (1.f / 64.f) - mu * mu;
  float rs = rsqrtf(var + 1e-5f);
  if (strm == 0) {
    f16x8 zz;
#pragma unroll
    for (int c = 0; c < 8; ++c)
      zz[c] = (_Float16)((v[c] - mu) * rs * g[8 * sub + c] + be[8 * sub + c]);
    *(f16x8*)(z + (size_t)w * 64 + 8 * sub) = zz;
  }
}

// ---------------- decode: 8 pairs per wave, 8 lanes per pair, fdot2 ----------------
__global__ __launch_bounds__(256) void decode(const _Float16* __restrict__ z,
                                              const int* __restrict__ eli,
                                              float* __restrict__ out, int EL) {
  int wv = threadIdx.x >> 6, l = threadIdx.x & 63;
  int sub = l & 7;
  int pidx = (blockIdx.x * 4 + wv) * 8 + (l >> 3);
  if (pidx >= EL) return;
  int a = eli[pidx], b = eli[EL + pidx];
  f16x8 za = *(const f16x8*)(z + (size_t)a * 64 + 8 * sub);
  f16x8 zb = *(const f16x8*)(z + (size_t)b * 64 + 8 * sub);
  const f16x2* za2 = (const f16x2*)&za;
  const f16x2* zb2 = (const f16x2*)&zb;
  float p = 0.f;
#pragma unroll
  for (int q = 0; q < 4; ++q) p = __builtin_amdgcn_fdot2(za2[q], zb2[q], p, false);
  p = dpp_add<0xB1>(p);
  p = dpp_add<0x4E>(p);
  p = swz_add<0x101F>(p);
  if (sub == 0) out[pidx] = p;
}

extern "C" void kernel_launch(void* const* d_in, const int* in_sizes, int n_in, void* d_out,
                              int out_size, void* d_ws, size_t ws_size, hipStream_t stream) {
  const float* x = (const float*)d_in[0];
  const int* ei = (const int*)d_in[1];
  const int* eli = (const int*)d_in[2];
  const float* W1l = (const float*)d_in[3];
  const float* b1l = (const float*)d_in[4];
  const float* W1r = (const float*)d_in[5];
  const float* b1r = (const float*)d_in[6];
  const float* att1 = (const float*)d_in[7];
  const float* bias1 = (const float*)d_in[8];
  const float* g1 = (const float*)d_in[9];
  const float* be1 = (const float*)d_in[10];
  const float* W2l = (const float*)d_in[11];
  const float* b2l = (const float*)d_in[12];
  const float* W2r = (const float*)d_in[13];
  const float* b2r = (const float*)d_in[14];
  const float* att2 = (const float*)d_in[15];
  const float* bias2 = (const float*)d_in[16];
  const float* g2 = (const float*)d_in[17];
  const float* be2 = (const float*)d_in[18];

  const int N = in_sizes[0] / 128;
  const int E = in_sizes[1] / 2;
  const int EL = in_sizes[2] / 2;
  const int ET = E + N;

  char* base = (char*)d_ws;
  _Float16* xl16 = (_Float16*)base;                                  // N*128 f16
  _Float16* xr16 = (_Float16*)(base + (size_t)N * 256);              // N*128 f16
  unsigned short* h_bf = (unsigned short*)(base + (size_t)N * 512);  // N*128 bf16
  _Float16* hl16 = (_Float16*)(base + (size_t)N * 768);              // N*64 f16
  _Float16* hr16 = (_Float16*)(base + (size_t)N * 896);              // N*64 f16
  _Float16* z16 = (_Float16*)(base + (size_t)N * 1024);              // N*64 f16
  int* ib = (int*)(base + (size_t)N * 1152);
  int* cnt = ib;
  int* cur = ib + N;
  int* rowptr = ib + 2 * N;
  int* part = ib + 3 * N + 2;
  int* adj = ib + 3 * N + 258;
  size_t ints_bytes = ((size_t)(3 * N + 258) + (size_t)ET) * 4;
  unsigned short* wbuf =
      (unsigned short*)(base + (((size_t)N * 1152 + ints_bytes + 255) & ~(size_t)255));

  const int n4 = (N + 3) / 4;
  prep0<<<64, 256, 0, stream>>>(W1l, W1r, W2l, W2r, wbuf, (int4*)cnt, n4);

  const int eB = (ET + 255) / 256;
  const int Mtiles = (N + 15) / 16;
  const int pBlocks = (Mtiles + 3) / 4;
  const int Nper = (N + 7) / 8;
  projdeg<<<pBlocks + 8 * eB, 256, 0, stream>>>(x, wbuf, b1l, b1r, xl16, xr16, Mtiles, pBlocks,
                                                ei, cnt, E, ET, Nper);

  const int nB = (N + 255) / 256;
  scanA<<<nB, 256, 0, stream>>>(cnt, part, N);
  scanB<<<1, 256, 0, stream>>>(part, rowptr, nB, N);
  scanC<<<nB, 256, 0, stream>>>(cnt, part, rowptr, cur, N);

  scatter_part<<<8 * eB, 256, 0, stream>>>(ei, cur, adj, E, ET, Nper);

  const int gB = (N + 3) / 4;
  gat1<<<gB, 256, 0, stream>>>(xl16, xr16, h_bf, rowptr, adj, att1, bias1, g1, be1, N);

  proj_mfma<unsigned short, 64>
      <<<pBlocks, 256, 0, stream>>>(h_bf, wbuf + 32768, b2l, b2r, hl16, hr16, Mtiles);

  gat2<<<gB, 256, 0, stream>>>(hl16, hr16, rowptr, adj, att2, bias2, g2, be2, z16, N);

  const int dBlocks = (EL + 31) / 32;
  decode<<<dBlocks, 256, 0, stream>>>(z16, eli, (float*)d_out, EL);
}

// Round 20
// 180.672 us; speedup vs baseline: 1.0382x; 1.0137x over previous
//
#include <hip/hip_runtime.h>
#include <hip/hip_bf16.h>

// GATv2 link predictor: N=50000, E=800000 (+N self loops), IN=128, HID=32, HEADS=4, OUT=64
// f32 in/out. CSR + fused GAT layers, shift-invariant softmax, pk-f16 logit math, f32 accum.
// bf16 MFMA projections (swapped operand, pre-swizzled W image). XCD-partitioned scatter.
// This is the round-17 configuration (best measured: 180.7us). r18 (no-LDS proj) = 187.6,
// r19 (XCD-partitioned fused deg) = 183.2 — both theories falsified; projdeg's ~51us is
// latency-bound invariant to LDS/occupancy/VGPR/atomic-partitioning.

#define DEVFN __device__ __forceinline__

typedef __attribute__((ext_vector_type(4))) float f32x4;
typedef __attribute__((ext_vector_type(8))) short bf16x8;
typedef _Float16 f16x2 __attribute__((ext_vector_type(2)));
typedef _Float16 f16x8 __attribute__((ext_vector_type(8)));

DEVFN unsigned short f2bf(float f) {  // RNE f32->bf16
  unsigned u = __float_as_uint(f);
  return (unsigned short)((u + 0x7fffu + ((u >> 16) & 1u)) >> 16);
}

DEVFN f16x2 pkrtz(float a, float b) {
  auto r = __builtin_amdgcn_cvt_pkrtz(a, b);
  union { decltype(r) s; f16x2 d; } u;
  u.s = r;
  return u.d;
}

template <int CTRL>
DEVFN float dpp_add(float s) {
  int x = __builtin_amdgcn_update_dpp(0, __float_as_int(s), CTRL, 0xF, 0xF, true);
  return s + __int_as_float(x);
}
template <int OFF>
DEVFN float swz_add(float s) {
  int x = __builtin_amdgcn_ds_swizzle(__float_as_int(s), OFF);
  return s + __int_as_float(x);
}

DEVFN bf16x8 load_frag(const float* p) {
  f32x4 u = *(const f32x4*)p;
  f32x4 v = *(const f32x4*)(p + 4);
  union { unsigned r[4]; bf16x8 h; } o;
  asm("v_cvt_pk_bf16_f32 %0, %1, %2" : "=v"(o.r[0]) : "v"(u[0]), "v"(u[1]));
  asm("v_cvt_pk_bf16_f32 %0, %1, %2" : "=v"(o.r[1]) : "v"(u[2]), "v"(u[3]));
  asm("v_cvt_pk_bf16_f32 %0, %1, %2" : "=v"(o.r[2]) : "v"(v[0]), "v"(v[1]));
  asm("v_cvt_pk_bf16_f32 %0, %1, %2" : "=v"(o.r[3]) : "v"(v[2]), "v"(v[3]));
  return o.h;
}
DEVFN bf16x8 load_frag(const unsigned short* p) { return *(const bf16x8*)p; }

// ---------------- prep0: W->bf16 swizzled image + zero cnt ----------------
__global__ __launch_bounds__(256) void prep0(const float* __restrict__ W1l,
                                             const float* __restrict__ W1r,
                                             const float* __restrict__ W2l,
                                             const float* __restrict__ W2r,
                                             unsigned short* __restrict__ wbuf,
                                             int4* __restrict__ cnt4, int n4) {
  int t = blockIdx.x * 256 + threadIdx.x;
  if (t < 16384) {  // W1: [128][128]
    int k = t >> 7, o = t & 127;
    unsigned off = ((unsigned)(o * 256 + k * 2)) ^ ((unsigned)(o & 7) << 4);
    wbuf[off >> 1] = f2bf(W1l[t]);
    wbuf[16384 + (off >> 1)] = f2bf(W1r[t]);
  }
  if (t < 8192) {  // W2: [128][64]
    int k = t >> 6, o = t & 63;
    unsigned off = ((unsigned)(o * 256 + k * 2)) ^ ((unsigned)(o & 7) << 4);
    wbuf[32768 + (off >> 1)] = f2bf(W2l[t]);
    wbuf[40960 + (off >> 1)] = f2bf(W2r[t]);
  }
  if (t < n4) cnt4[t] = make_int4(0, 0, 0, 0);
}

// ---------------- projdeg: proj1 (MFMA, LDS-staged W) + degree count, fused dispatch -------
__global__ __launch_bounds__(256) void projdeg(const float* __restrict__ X,
                                               const unsigned short* __restrict__ wsrc,
                                               const float* __restrict__ Ba,
                                               const float* __restrict__ Bb,
                                               _Float16* __restrict__ Ya,
                                               _Float16* __restrict__ Yb, int Mtiles, int pBlocks,
                                               const int* __restrict__ ei, int* __restrict__ cnt,
                                               int E, int ET) {
  constexpr int DOUT = 128;
  constexpr int NPM = DOUT / 16;
  constexpr unsigned MATB = DOUT * 256;
  __shared__ unsigned short sW[2 * DOUT * 128];
  if (blockIdx.x >= pBlocks) {  // degree-count blocks
    int t = (blockIdx.x - pBlocks) * 256 + threadIdx.x;
    if (t < ET) {
      int dst = (t < E) ? ei[E + t] : (t - E);
      atomicAdd(&cnt[dst], 1);
    }
    return;
  }
  const int t = threadIdx.x;
  {  // stage pre-swizzled image (pure memcpy)
    const char* gsrc = (const char*)wsrc;
    char* lds = (char*)sW;
    for (unsigned off = t * 16; off < 2 * MATB; off += 256 * 16)
      *(uint4*)(lds + off) = *(const uint4*)(gsrc + off);
  }
  __syncthreads();
  const int l = t & 63, wv = t >> 6;
  const int mt = blockIdx.x * 4 + wv;
  if (mt >= Mtiles) return;
  const int r15 = l & 15, kq = l >> 4;

  bf16x8 a0[4];
  {
    const float* px = X + ((size_t)(mt * 16 + r15)) * 128 + kq * 8;
#pragma unroll
    for (int ks = 0; ks < 4; ++ks) a0[ks] = load_frag(px + ks * 32);
  }

  for (int nt = 0; nt < 2 * NPM; ++nt) {
    const int mat = nt / NPM;
    const int o = (nt % NPM) * 16 + r15;
    bf16x8 b[4];
#pragma unroll
    for (int ks = 0; ks < 4; ++ks) {
      unsigned byteoff =
          (((unsigned)(o * 256 + (ks * 32 + kq * 8) * 2)) ^ ((unsigned)(o & 7) << 4)) +
          (unsigned)mat * MATB;
      b[ks] = *(const bf16x8*)((const char*)sW + byteoff);
    }
    f32x4 c0 = {0.f, 0.f, 0.f, 0.f};
#pragma unroll
    for (int ks = 0; ks < 4; ++ks)
      c0 = __builtin_amdgcn_mfma_f32_16x16x32_bf16(b[ks], a0[ks], c0, 0, 0, 0);
    _Float16* Y = mat ? Yb : Ya;
    const float* Bv = mat ? Bb : Ba;
    const int obase = (nt % NPM) * 16 + 4 * kq;
    float4 b4 = *(const float4*)(Bv + obase);
    union { f16x2 h[2]; uint2 u; } pk;
    pk.h[0] = pkrtz(c0[0] + b4.x, c0[1] + b4.y);
    pk.h[1] = pkrtz(c0[2] + b4.z, c0[3] + b4.w);
    *(uint2*)(Y + (size_t)(mt * 16 + r15) * DOUT + obase) = pk.u;
  }
}

// ---------------- CSR scan: 3-kernel parallel version ----------------
__global__ __launch_bounds__(256) void scanA(const int* __restrict__ cnt, int* __restrict__ part,
                                             int N) {
  int i = blockIdx.x * 256 + threadIdx.x;
  int v = (i < N) ? cnt[i] : 0;
  __shared__ int wsm[4];
  int lane = threadIdx.x & 63, wid = threadIdx.x >> 6;
#pragma unroll
  for (int o = 1; o < 64; o <<= 1) v += __shfl_xor(v, o);
  if (lane == 0) wsm[wid] = v;
  __syncthreads();
  if (threadIdx.x == 0) part[blockIdx.x] = wsm[0] + wsm[1] + wsm[2] + wsm[3];
}

__global__ __launch_bounds__(256) void scanB(int* __restrict__ part, int* __restrict__ rowptr,
                                             int Bs, int N) {
  int t = threadIdx.x;
  int v = (t < Bs) ? part[t] : 0;
  int lane = t & 63, wid = t >> 6;
  int s = v;
#pragma unroll
  for (int o = 1; o < 64; o <<= 1) {
    int u = __shfl_up(s, o);
    if (lane >= o) s += u;
  }
  __shared__ int wsm[4];
  if (lane == 63) wsm[wid] = s;
  __syncthreads();
  int woff = 0;
  for (int k = 0; k < wid; k++) woff += wsm[k];
  if (t < Bs) part[t] = woff + s - v;
  if (t == 0) rowptr[N] = wsm[0] + wsm[1] + wsm[2] + wsm[3];
}

// writes exclusive prefix to rowptr AND cur (cur = scatter write cursor)
__global__ __launch_bounds__(256) void scanC(const int* __restrict__ cnt,
                                             const int* __restrict__ part,
                                             int* __restrict__ rowptr, int* __restrict__ cur,
                                             int N) {
  int i = blockIdx.x * 256 + threadIdx.x;
  int v = (i < N) ? cnt[i] : 0;
  int lane = threadIdx.x & 63, wid = threadIdx.x >> 6;
  int s = v;
#pragma unroll
  for (int o = 1; o < 64; o <<= 1) {
    int u = __shfl_up(s, o);
    if (lane >= o) s += u;
  }
  __shared__ int wsm[4];
  if (lane == 63) wsm[wid] = s;
  __syncthreads();
  int woff = 0;
  for (int k = 0; k < wid; k++) woff += wsm[k];
  if (i < N) {
    int val = part[blockIdx.x] + woff + s - v;
    rowptr[i] = val;
    cur[i] = val;
  }
}

// ---------------- scatter, XCD-partitioned by dst range; cur pre-seeded with rowptr --------
__global__ __launch_bounds__(256) void scatter_part(const int* __restrict__ ei,
                                                    int* __restrict__ cur, int* __restrict__ adj,
                                                    int E, int ET, int Nper) {
  int part = blockIdx.x & 7;
  int t = (blockIdx.x >> 3) * 256 + threadIdx.x;
  if (t >= ET) return;
  int dst = (t < E) ? ei[E + t] : (t - E);
  if ((unsigned)(dst - part * Nper) < (unsigned)Nper) {
    int src = (t < E) ? ei[t] : dst;
    int pos = atomicAdd(&cur[dst], 1);
    adj[pos] = src;
  }
}

// ---------------- proj2 via MFMA (swapped operands, LDS-staged W image) ----------------
template <typename TIN, int DOUT>
__global__ __launch_bounds__(256) void proj_mfma(const TIN* __restrict__ X,
                                                 const unsigned short* __restrict__ wsrc,
                                                 const float* __restrict__ Ba,
                                                 const float* __restrict__ Bb,
                                                 _Float16* __restrict__ Ya,
                                                 _Float16* __restrict__ Yb, int Mtiles) {
  constexpr int NPM = DOUT / 16;
  constexpr unsigned MATB = DOUT * 256;
  __shared__ unsigned short sW[2 * DOUT * 128];
  const int t = threadIdx.x;
  {
    const char* gsrc = (const char*)wsrc;
    char* lds = (char*)sW;
    for (unsigned off = t * 16; off < 2 * MATB; off += 256 * 16)
      *(uint4*)(lds + off) = *(const uint4*)(gsrc + off);
  }
  __syncthreads();
  const int l = t & 63, wv = t >> 6;
  const int mt = blockIdx.x * 4 + wv;
  if (mt >= Mtiles) return;
  const int r15 = l & 15, kq = l >> 4;

  bf16x8 a0[4];
  {
    const TIN* px = X + ((size_t)(mt * 16 + r15)) * 128 + kq * 8;
#pragma unroll
    for (int ks = 0; ks < 4; ++ks) a0[ks] = load_frag(px + ks * 32);
  }

  for (int nt = 0; nt < 2 * NPM; ++nt) {
    const int mat = nt / NPM;
    const int o = (nt % NPM) * 16 + r15;
    bf16x8 b[4];
#pragma unroll
    for (int ks = 0; ks < 4; ++ks) {
      unsigned byteoff =
          (((unsigned)(o * 256 + (ks * 32 + kq * 8) * 2)) ^ ((unsigned)(o & 7) << 4)) +
          (unsigned)mat * MATB;
      b[ks] = *(const bf16x8*)((const char*)sW + byteoff);
    }
    f32x4 c0 = {0.f, 0.f, 0.f, 0.f};
#pragma unroll
    for (int ks = 0; ks < 4; ++ks)
      c0 = __builtin_amdgcn_mfma_f32_16x16x32_bf16(b[ks], a0[ks], c0, 0, 0, 0);
    _Float16* Y = mat ? Yb : Ya;
    const float* Bv = mat ? Bb : Ba;
    const int obase = (nt % NPM) * 16 + 4 * kq;
    float4 b4 = *(const float4*)(Bv + obase);
    union { f16x2 h[2]; uint2 u; } pk;
    pk.h[0] = pkrtz(c0[0] + b4.x, c0[1] + b4.y);
    pk.h[1] = pkrtz(c0[2] + b4.z, c0[3] + b4.w);
    *(uint2*)(Y + (size_t)(mt * 16 + r15) * DOUT + obase) = pk.u;
  }
}

// ---------------- fused GAT layer 1: wave/dst, 4 streams x 16 lanes, 8ch/lane --------------
// head = sub>>2; per-head logit = xor1+xor2 over subs {4h..4h+3} = ch [32h,32h+32).
__global__ __launch_bounds__(256) void gat1(const _Float16* __restrict__ xl,
                                            const _Float16* __restrict__ xr,
                                            unsigned short* __restrict__ h_out,
                                            const int* __restrict__ rowptr,
                                            const int* __restrict__ adj,
                                            const float* __restrict__ att,
                                            const float* __restrict__ bias,
                                            const float* __restrict__ g,
                                            const float* __restrict__ be, int N) {
  int w = blockIdx.x * 4 + (threadIdx.x >> 6);
  int l = threadIdx.x & 63;
  if (w >= N) return;
  int sub = l & 15, strm = l >> 4;
  f16x8 xr8 = *(const f16x8*)(xr + (size_t)w * 128 + 8 * sub);
  const f16x2* xr2 = (const f16x2*)&xr8;
  f16x2 at2[4];
#pragma unroll
  for (int q = 0; q < 4; ++q) {
    at2[q][0] = (_Float16)att[8 * sub + 2 * q];
    at2[q][1] = (_Float16)att[8 * sub + 2 * q + 1];
  }
  float den = 0.f;
  float acc[8] = {0.f, 0.f, 0.f, 0.f, 0.f, 0.f, 0.f, 0.f};
  int j0 = rowptr[w], j1 = rowptr[w + 1];

  auto proc = [&](f16x8 a8) {
    const f16x2* a2 = (const f16x2*)&a8;
    float s = 0.f;
#pragma unroll
    for (int q = 0; q < 4; ++q) {
      f16x2 e = a2[q] + xr2[q];
      e = __builtin_elementwise_max(e, e * (_Float16)0.2f);
      s = __builtin_amdgcn_fdot2(e, at2[q], s, false);
    }
    s = dpp_add<0xB1>(s);  // xor1
    s = dpp_add<0x4E>(s);  // xor2 -> full 32-ch head logit
    float p = __expf(s);   // shift-invariant: no max subtraction needed in f32
    den += p;
#pragma unroll
    for (int c = 0; c < 8; ++c) acc[c] = fmaf((float)a8[c], p, acc[c]);  // v_fma_mix
  };

  int j = j0 + strm;
  if (j < j1) {
    f16x8 a = *(const f16x8*)(xl + (size_t)adj[j] * 128 + 8 * sub);
    for (j += 4; j < j1; j += 4) {
      f16x8 an = *(const f16x8*)(xl + (size_t)adj[j] * 128 + 8 * sub);
      proc(a);
      a = an;
    }
    proc(a);
  }

  // merge 4 streams: plain sums (shared implicit offset)
  den = swz_add<0x401F>(den);
#pragma unroll
  for (int c = 0; c < 8; ++c) acc[c] = swz_add<0x401F>(acc[c]);
  den += __shfl_xor(den, 32);
#pragma unroll
  for (int c = 0; c < 8; ++c) acc[c] += __shfl_xor(acc[c], 32);

  float inv = 1.f / (den + 1e-16f);
  float v[8], s1 = 0.f, s2 = 0.f;
#pragma unroll
  for (int c = 0; c < 8; ++c) {
    v[c] = fmaf(acc[c], inv, bias[8 * sub + c]);
    s1 += v[c];
    s2 = fmaf(v[c], v[c], s2);
  }
  s1 = dpp_add<0xB1>(s1); s2 = dpp_add<0xB1>(s2);
  s1 = dpp_add<0x4E>(s1); s2 = dpp_add<0x4E>(s2);
  s1 = swz_add<0x101F>(s1); s2 = swz_add<0x101F>(s2);  // xor4
  s1 = swz_add<0x201F>(s1); s2 = swz_add<0x201F>(s2);  // xor8
  float mu = s1 * (1.f / 128.f);
  float var = s2 * (1.f / 128.f) - mu * mu;
  float rs = rsqrtf(var + 1e-5f);
  if (strm == 0) {
    unsigned short o8[8];
#pragma unroll
    for (int c = 0; c < 8; ++c) {
      float r = (v[c] - mu) * rs * g[8 * sub + c] + be[8 * sub + c];
      r = r > 0.f ? r : __expf(r) - 1.f;  // ELU
      o8[c] = f2bf(r);
    }
    *(uint4*)(h_out + (size_t)w * 128 + 8 * sub) = *(const uint4*)o8;
  }
}

// ---------------- fused GAT layer 2: wave/dst, 8 streams x 8 lanes, 8ch/lane ---------------
__global__ __launch_bounds__(256) void gat2(const _Float16* __restrict__ hl,
                                            const _Float16* __restrict__ hr,
                                            const int* __restrict__ rowptr,
                                            const int* __restrict__ adj,
                                            const float* __restrict__ att,
                                            const float* __restrict__ bias,
                                            const float* __restrict__ g,
                                            const float* __restrict__ be,
                                            _Float16* __restrict__ z, int N) {
  int w = blockIdx.x * 4 + (threadIdx.x >> 6);
  int l = threadIdx.x & 63;
  if (w >= N) return;
  int sub = l & 7, strm = l >> 3;
  f16x8 xr8 = *(const f16x8*)(hr + (size_t)w * 64 + 8 * sub);
  const f16x2* xr2 = (const f16x2*)&xr8;
  f16x2 at2[4];
#pragma unroll
  for (int q = 0; q < 4; ++q) {
    at2[q][0] = (_Float16)att[8 * sub + 2 * q];
    at2[q][1] = (_Float16)att[8 * sub + 2 * q + 1];
  }
  float den = 0.f;
  float acc[8] = {0.f, 0.f, 0.f, 0.f, 0.f, 0.f, 0.f, 0.f};
  int j0 = rowptr[w], j1 = rowptr[w + 1];

  auto proc = [&](f16x8 a8) {
    const f16x2* a2 = (const f16x2*)&a8;
    float s = 0.f;
#pragma unroll
    for (int q = 0; q < 4; ++q) {
      f16x2 e = a2[q] + xr2[q];
      e = __builtin_elementwise_max(e, e * (_Float16)0.2f);
      s = __builtin_amdgcn_fdot2(e, at2[q], s, false);
    }
    s = dpp_add<0xB1>(s);
    s = dpp_add<0x4E>(s);
    s = swz_add<0x101F>(s);  // xor4 -> full 64-ch (single-head) logit
    float p = __expf(s);
    den += p;
#pragma unroll
    for (int c = 0; c < 8; ++c) acc[c] = fmaf((float)a8[c], p, acc[c]);
  };

  int j = j0 + strm;
  if (j < j1) {
    f16x8 a = *(const f16x8*)(hl + (size_t)adj[j] * 64 + 8 * sub);
    for (j += 8; j < j1; j += 8) {
      f16x8 an = *(const f16x8*)(hl + (size_t)adj[j] * 64 + 8 * sub);
      proc(a);
      a = an;
    }
    proc(a);
  }

  den = swz_add<0x201F>(den);
#pragma unroll
  for (int c = 0; c < 8; ++c) acc[c] = swz_add<0x201F>(acc[c]);
  den = swz_add<0x401F>(den);
#pragma unroll
  for (int c = 0; c < 8; ++c) acc[c] = swz_add<0x401F>(acc[c]);
  den += __shfl_xor(den, 32);
#pragma unroll
  for (int c = 0; c < 8; ++c) acc[c] += __shfl_xor(acc[c], 32);

  float inv = 1.f / (den + 1e-16f);
  float v[8], s1 = 0.f, s2 = 0.f;
#pragma unroll
  for (int c = 0; c < 8; ++c) {
    v[c] = fmaf(acc[c], inv, bias[8 * sub + c]);
    s1 += v[c];
    s2 = fmaf(v[c], v[c], s2);
  }
  s1 = dpp_add<0xB1>(s1); s2 = dpp_add<0xB1>(s2);
  s1 = dpp_add<0x4E>(s1); s2 = dpp_add<0x4E>(s2);
  s1 = swz_add<0x101F>(s1); s2 = swz_add<0x101F>(s2);
  float mu = s1 * (1.f / 64.f);
  float var = s2 * (1.f / 64.f) - mu * mu;
  float rs = rsqrtf(var + 1e-5f);
  if (strm == 0) {
    f16x8 zz;
#pragma unroll
    for (int c = 0; c < 8; ++c)
      zz[c] = (_Float16)((v[c] - mu) * rs * g[8 * sub + c] + be[8 * sub + c]);
    *(f16x8*)(z + (size_t)w * 64 + 8 * sub) = zz;
  }
}

// ---------------- decode: 8 pairs per wave, 8 lanes per pair, fdot2 ----------------
__global__ __launch_bounds__(256) void decode(const _Float16* __restrict__ z,
                                              const int* __restrict__ eli,
                                              float* __restrict__ out, int EL) {
  int wv = threadIdx.x >> 6, l = threadIdx.x & 63;
  int sub = l & 7;
  int pidx = (blockIdx.x * 4 + wv) * 8 + (l >> 3);
  if (pidx >= EL) return;
  int a = eli[pidx], b = eli[EL + pidx];
  f16x8 za = *(const f16x8*)(z + (size_t)a * 64 + 8 * sub);
  f16x8 zb = *(const f16x8*)(z + (size_t)b * 64 + 8 * sub);
  const f16x2* za2 = (const f16x2*)&za;
  const f16x2* zb2 = (const f16x2*)&zb;
  float p = 0.f;
#pragma unroll
  for (int q = 0; q < 4; ++q) p = __builtin_amdgcn_fdot2(za2[q], zb2[q], p, false);
  p = dpp_add<0xB1>(p);
  p = dpp_add<0x4E>(p);
  p = swz_add<0x101F>(p);
  if (sub == 0) out[pidx] = p;
}

extern "C" void kernel_launch(void* const* d_in, const int* in_sizes, int n_in, void* d_out,
                              int out_size, void* d_ws, size_t ws_size, hipStream_t stream) {
  const float* x = (const float*)d_in[0];
  const int* ei = (const int*)d_in[1];
  const int* eli = (const int*)d_in[2];
  const float* W1l = (const float*)d_in[3];
  const float* b1l = (const float*)d_in[4];
  const float* W1r = (const float*)d_in[5];
  const float* b1r = (const float*)d_in[6];
  const float* att1 = (const float*)d_in[7];
  const float* bias1 = (const float*)d_in[8];
  const float* g1 = (const float*)d_in[9];
  const float* be1 = (const float*)d_in[10];
  const float* W2l = (const float*)d_in[11];
  const float* b2l = (const float*)d_in[12];
  const float* W2r = (const float*)d_in[13];
  const float* b2r = (const float*)d_in[14];
  const float* att2 = (const float*)d_in[15];
  const float* bias2 = (const float*)d_in[16];
  const float* g2 = (const float*)d_in[17];
  const float* be2 = (const float*)d_in[18];

  const int N = in_sizes[0] / 128;
  const int E = in_sizes[1] / 2;
  const int EL = in_sizes[2] / 2;
  const int ET = E + N;

  char* base = (char*)d_ws;
  _Float16* xl16 = (_Float16*)base;                                  // N*128 f16
  _Float16* xr16 = (_Float16*)(base + (size_t)N * 256);              // N*128 f16
  unsigned short* h_bf = (unsigned short*)(base + (size_t)N * 512);  // N*128 bf16
  _Float16* hl16 = (_Float16*)(base + (size_t)N * 768);              // N*64 f16
  _Float16* hr16 = (_Float16*)(base + (size_t)N * 896);              // N*64 f16
  _Float16* z16 = (_Float16*)(base + (size_t)N * 1024);              // N*64 f16
  int* ib = (int*)(base + (size_t)N * 1152);
  int* cnt = ib;
  int* cur = ib + N;
  int* rowptr = ib + 2 * N;
  int* part = ib + 3 * N + 2;
  int* adj = ib + 3 * N + 258;
  size_t ints_bytes = ((size_t)(3 * N + 258) + (size_t)ET) * 4;
  unsigned short* wbuf =
      (unsigned short*)(base + (((size_t)N * 1152 + ints_bytes + 255) & ~(size_t)255));

  const int n4 = (N + 3) / 4;
  prep0<<<64, 256, 0, stream>>>(W1l, W1r, W2l, W2r, wbuf, (int4*)cnt, n4);

  const int eB = (ET + 255) / 256;
  const int Mtiles = (N + 15) / 16;
  const int pBlocks = (Mtiles + 3) / 4;
  projdeg<<<pBlocks + eB, 256, 0, stream>>>(x, wbuf, b1l, b1r, xl16, xr16, Mtiles, pBlocks, ei,
                                            cnt, E, ET);

  const int nB = (N + 255) / 256;
  scanA<<<nB, 256, 0, stream>>>(cnt, part, N);
  scanB<<<1, 256, 0, stream>>>(part, rowptr, nB, N);
  scanC<<<nB, 256, 0, stream>>>(cnt, part, rowptr, cur, N);

  const int Nper = (N + 7) / 8;
  scatter_part<<<8 * eB, 256, 0, stream>>>(ei, cur, adj, E, ET, Nper);

  const int gB = (N + 3) / 4;
  gat1<<<gB, 256, 0, stream>>>(xl16, xr16, h_bf, rowptr, adj, att1, bias1, g1, be1, N);

  proj_mfma<unsigned short, 64>
      <<<pBlocks, 256, 0, stream>>>(h_bf, wbuf + 32768, b2l, b2r, hl16, hr16, Mtiles);

  gat2<<<gB, 256, 0, stream>>>(hl16, hr16, rowptr, adj, att2, bias2, g2, be2, z16, N);

  const int dBlocks = (EL + 31) / 32;
  decode<<<dBlocks, 256, 0, stream>>>(z16, eli, (float*)d_out, EL);
}

// Round 21
// 179.228 us; speedup vs baseline: 1.0466x; 1.0081x over previous
//
#include <hip/hip_runtime.h>
#include <hip/hip_bf16.h>

// GATv2 link predictor: N=50000, E=800000 (+N self loops), IN=128, HID=32, HEADS=4, OUT=64
// f32 in/out. CSR + fused GAT layers, shift-invariant softmax, pk-f16 logit math, f32 accum.
// bf16 MFMA projections (swapped operand, pre-swizzled W image). XCD-partitioned scatter.
// Round 21: proj stores were 8B/lane fragments scattered in time -> partial-line HBM
// read-modify-write (WRITE_SIZE 50MB for 25.6MB payload, ~1.3TB/s effective). Fix: per-wave
// LDS transpose tile, then fully-coalesced 16B/lane stores. W staged one matrix at a time
// to fund the transpose LDS (49KB total -> 3 blocks/CU).

#define DEVFN __device__ __forceinline__

typedef __attribute__((ext_vector_type(4))) float f32x4;
typedef __attribute__((ext_vector_type(8))) short bf16x8;
typedef _Float16 f16x2 __attribute__((ext_vector_type(2)));
typedef _Float16 f16x8 __attribute__((ext_vector_type(8)));

DEVFN unsigned short f2bf(float f) {  // RNE f32->bf16
  unsigned u = __float_as_uint(f);
  return (unsigned short)((u + 0x7fffu + ((u >> 16) & 1u)) >> 16);
}

DEVFN f16x2 pkrtz(float a, float b) {
  auto r = __builtin_amdgcn_cvt_pkrtz(a, b);
  union { decltype(r) s; f16x2 d; } u;
  u.s = r;
  return u.d;
}

template <int CTRL>
DEVFN float dpp_add(float s) {
  int x = __builtin_amdgcn_update_dpp(0, __float_as_int(s), CTRL, 0xF, 0xF, true);
  return s + __int_as_float(x);
}
template <int OFF>
DEVFN float swz_add(float s) {
  int x = __builtin_amdgcn_ds_swizzle(__float_as_int(s), OFF);
  return s + __int_as_float(x);
}

DEVFN bf16x8 load_frag(const float* p) {
  f32x4 u = *(const f32x4*)p;
  f32x4 v = *(const f32x4*)(p + 4);
  union { unsigned r[4]; bf16x8 h; } o;
  asm("v_cvt_pk_bf16_f32 %0, %1, %2" : "=v"(o.r[0]) : "v"(u[0]), "v"(u[1]));
  asm("v_cvt_pk_bf16_f32 %0, %1, %2" : "=v"(o.r[1]) : "v"(u[2]), "v"(u[3]));
  asm("v_cvt_pk_bf16_f32 %0, %1, %2" : "=v"(o.r[2]) : "v"(v[0]), "v"(v[1]));
  asm("v_cvt_pk_bf16_f32 %0, %1, %2" : "=v"(o.r[3]) : "v"(v[2]), "v"(v[3]));
  return o.h;
}
DEVFN bf16x8 load_frag(const unsigned short* p) { return *(const bf16x8*)p; }

// ---------------- shared projection body: MFMA + LDS-transpose coalesced stores ----------
// smem layout: [0, MATB) staged W image (one matrix at a time); [MATB, ...) per-wave
// transpose tiles: 4 waves x 16 rows x (ROWB+16) bytes.
template <typename TIN, int DOUT>
DEVFN void proj_body(const TIN* __restrict__ X, const unsigned short* __restrict__ wsrc,
                     const float* __restrict__ Ba, const float* __restrict__ Bb,
                     _Float16* __restrict__ Ya, _Float16* __restrict__ Yb, int Mtiles,
                     int blockId, char* smem) {
  constexpr int NPM = DOUT / 16;
  constexpr unsigned MATB = DOUT * 256;
  constexpr int ROWB = DOUT * 2;
  constexpr int PADROW = ROWB + 16;
  unsigned short* sW = (unsigned short*)smem;
  const int t = threadIdx.x;
  const int l = t & 63, wv = t >> 6;
  const int mt = blockId * 4 + wv;
  const bool active = mt < Mtiles;
  const int r15 = l & 15, kq = l >> 4;
  char* trw = smem + MATB + wv * (16 * PADROW);

  bf16x8 a0[4];
  if (active) {
    const TIN* px = X + ((size_t)(mt * 16 + r15)) * 128 + kq * 8;
#pragma unroll
    for (int ks = 0; ks < 4; ++ks) a0[ks] = load_frag(px + ks * 32);
  }

#pragma unroll
  for (int mat = 0; mat < 2; ++mat) {
    if (mat) __syncthreads();  // all reads of previous image done before restage
    {
      const char* gsrc = (const char*)wsrc + (unsigned)mat * MATB;
      for (unsigned off = t * 16; off < MATB; off += 256 * 16)
        *(uint4*)(smem + off) = *(const uint4*)(gsrc + off);
    }
    __syncthreads();
    if (active) {
      const float* Bv = mat ? Bb : Ba;
      _Float16* Y = mat ? Yb : Ya;
#pragma unroll
      for (int q = 0; q < NPM; ++q) {
        const int o = q * 16 + r15;
        bf16x8 b[4];
#pragma unroll
        for (int ks = 0; ks < 4; ++ks) {
          unsigned byteoff =
              ((unsigned)(o * 256 + (ks * 32 + kq * 8) * 2)) ^ ((unsigned)(o & 7) << 4);
          b[ks] = *(const bf16x8*)((const char*)sW + byteoff);
        }
        f32x4 c0 = {0.f, 0.f, 0.f, 0.f};
#pragma unroll
        for (int ks = 0; ks < 4; ++ks)
          c0 = __builtin_amdgcn_mfma_f32_16x16x32_bf16(b[ks], a0[ks], c0, 0, 0, 0);
        const int obase = q * 16 + 4 * kq;
        float4 b4 = *(const float4*)(Bv + obase);
        union { f16x2 h[2]; uint2 u; } pk;
        pk.h[0] = pkrtz(c0[0] + b4.x, c0[1] + b4.y);
        pk.h[1] = pkrtz(c0[2] + b4.z, c0[3] + b4.w);
        *(uint2*)(trw + r15 * PADROW + obase * 2) = pk.u;  // 8B LDS write (2-way alias, free)
      }
      // coalesced store: tile = 16 consecutive rows x ROWB bytes, contiguous in Y
      char* gdst = (char*)(Y + (size_t)mt * 16 * DOUT);
      constexpr int ITERS = (16 * ROWB) / (64 * 16);
#pragma unroll
      for (int i = 0; i < ITERS; ++i) {
        int off = l * 16 + i * 1024;
        *(uint4*)(gdst + off) = *(const uint4*)(trw + (off / ROWB) * PADROW + (off % ROWB));
      }
    }
  }
}

// ---------------- prep0: W->bf16 swizzled image + zero cnt ----------------
__global__ __launch_bounds__(256) void prep0(const float* __restrict__ W1l,
                                             const float* __restrict__ W1r,
                                             const float* __restrict__ W2l,
                                             const float* __restrict__ W2r,
                                             unsigned short* __restrict__ wbuf,
                                             int4* __restrict__ cnt4, int n4) {
  int t = blockIdx.x * 256 + threadIdx.x;
  if (t < 16384) {  // W1: [128][128]
    int k = t >> 7, o = t & 127;
    unsigned off = ((unsigned)(o * 256 + k * 2)) ^ ((unsigned)(o & 7) << 4);
    wbuf[off >> 1] = f2bf(W1l[t]);
    wbuf[16384 + (off >> 1)] = f2bf(W1r[t]);
  }
  if (t < 8192) {  // W2: [128][64]
    int k = t >> 6, o = t & 63;
    unsigned off = ((unsigned)(o * 256 + k * 2)) ^ ((unsigned)(o & 7) << 4);
    wbuf[32768 + (off >> 1)] = f2bf(W2l[t]);
    wbuf[40960 + (off >> 1)] = f2bf(W2r[t]);
  }
  if (t < n4) cnt4[t] = make_int4(0, 0, 0, 0);
}

// ---------------- projdeg: proj1 + degree count, fused dispatch ----------------
__global__ __launch_bounds__(256) void projdeg(const float* __restrict__ X,
                                               const unsigned short* __restrict__ wsrc,
                                               const float* __restrict__ Ba,
                                               const float* __restrict__ Bb,
                                               _Float16* __restrict__ Ya,
                                               _Float16* __restrict__ Yb, int Mtiles, int pBlocks,
                                               const int* __restrict__ ei, int* __restrict__ cnt,
                                               int E, int ET) {
  __shared__ char smem[128 * 256 + 4 * 16 * (256 + 16)];  // 32KB W + 17KB transpose
  if (blockIdx.x >= pBlocks) {  // degree-count blocks (exit before any barrier)
    int t = (blockIdx.x - pBlocks) * 256 + threadIdx.x;
    if (t < ET) {
      int dst = (t < E) ? ei[E + t] : (t - E);
      atomicAdd(&cnt[dst], 1);
    }
    return;
  }
  proj_body<float, 128>(X, wsrc, Ba, Bb, Ya, Yb, Mtiles, blockIdx.x, smem);
}

// ---------------- proj2 ----------------
__global__ __launch_bounds__(256) void proj2(const unsigned short* __restrict__ X,
                                             const unsigned short* __restrict__ wsrc,
                                             const float* __restrict__ Ba,
                                             const float* __restrict__ Bb,
                                             _Float16* __restrict__ Ya,
                                             _Float16* __restrict__ Yb, int Mtiles) {
  __shared__ char smem[64 * 256 + 4 * 16 * (128 + 16)];  // 16KB W + 9KB transpose
  proj_body<unsigned short, 64>(X, wsrc, Ba, Bb, Ya, Yb, Mtiles, blockIdx.x, smem);
}

// ---------------- CSR scan: 3-kernel parallel version ----------------
__global__ __launch_bounds__(256) void scanA(const int* __restrict__ cnt, int* __restrict__ part,
                                             int N) {
  int i = blockIdx.x * 256 + threadIdx.x;
  int v = (i < N) ? cnt[i] : 0;
  __shared__ int wsm[4];
  int lane = threadIdx.x & 63, wid = threadIdx.x >> 6;
#pragma unroll
  for (int o = 1; o < 64; o <<= 1) v += __shfl_xor(v, o);
  if (lane == 0) wsm[wid] = v;
  __syncthreads();
  if (threadIdx.x == 0) part[blockIdx.x] = wsm[0] + wsm[1] + wsm[2] + wsm[3];
}

__global__ __launch_bounds__(256) void scanB(int* __restrict__ part, int* __restrict__ rowptr,
                                             int Bs, int N) {
  int t = threadIdx.x;
  int v = (t < Bs) ? part[t] : 0;
  int lane = t & 63, wid = t >> 6;
  int s = v;
#pragma unroll
  for (int o = 1; o < 64; o <<= 1) {
    int u = __shfl_up(s, o);
    if (lane >= o) s += u;
  }
  __shared__ int wsm[4];
  if (lane == 63) wsm[wid] = s;
  __syncthreads();
  int woff = 0;
  for (int k = 0; k < wid; k++) woff += wsm[k];
  if (t < Bs) part[t] = woff + s - v;
  if (t == 0) rowptr[N] = wsm[0] + wsm[1] + wsm[2] + wsm[3];
}

// writes exclusive prefix to rowptr AND cur (cur = scatter write cursor)
__global__ __launch_bounds__(256) void scanC(const int* __restrict__ cnt,
                                             const int* __restrict__ part,
                                             int* __restrict__ rowptr, int* __restrict__ cur,
                                             int N) {
  int i = blockIdx.x * 256 + threadIdx.x;
  int v = (i < N) ? cnt[i] : 0;
  int lane = threadIdx.x & 63, wid = threadIdx.x >> 6;
  int s = v;
#pragma unroll
  for (int o = 1; o < 64; o <<= 1) {
    int u = __shfl_up(s, o);
    if (lane >= o) s += u;
  }
  __shared__ int wsm[4];
  if (lane == 63) wsm[wid] = s;
  __syncthreads();
  int woff = 0;
  for (int k = 0; k < wid; k++) woff += wsm[k];
  if (i < N) {
    int val = part[blockIdx.x] + woff + s - v;
    rowptr[i] = val;
    cur[i] = val;
  }
}

// ---------------- scatter, XCD-partitioned by dst range; cur pre-seeded with rowptr --------
__global__ __launch_bounds__(256) void scatter_part(const int* __restrict__ ei,
                                                    int* __restrict__ cur, int* __restrict__ adj,
                                                    int E, int ET, int Nper) {
  int part = blockIdx.x & 7;
  int t = (blockIdx.x >> 3) * 256 + threadIdx.x;
  if (t >= ET) return;
  int dst = (t < E) ? ei[E + t] : (t - E);
  if ((unsigned)(dst - part * Nper) < (unsigned)Nper) {
    int src = (t < E) ? ei[t] : dst;
    int pos = atomicAdd(&cur[dst], 1);
    adj[pos] = src;
  }
}

// ---------------- fused GAT layer 1: wave/dst, 4 streams x 16 lanes, 8ch/lane --------------
// head = sub>>2; per-head logit = xor1+xor2 over subs {4h..4h+3} = ch [32h,32h+32).
__global__ __launch_bounds__(256) void gat1(const _Float16* __restrict__ xl,
                                            const _Float16* __restrict__ xr,
                                            unsigned short* __restrict__ h_out,
                                            const int* __restrict__ rowptr,
                                            const int* __restrict__ adj,
                                            const float* __restrict__ att,
                                            const float* __restrict__ bias,
                                            const float* __restrict__ g,
                                            const float* __restrict__ be, int N) {
  int w = blockIdx.x * 4 + (threadIdx.x >> 6);
  int l = threadIdx.x & 63;
  if (w >= N) return;
  int sub = l & 15, strm = l >> 4;
  f16x8 xr8 = *(const f16x8*)(xr + (size_t)w * 128 + 8 * sub);
  const f16x2* xr2 = (const f16x2*)&xr8;
  f16x2 at2[4];
#pragma unroll
  for (int q = 0; q < 4; ++q) {
    at2[q][0] = (_Float16)att[8 * sub + 2 * q];
    at2[q][1] = (_Float16)att[8 * sub + 2 * q + 1];
  }
  float den = 0.f;
  float acc[8] = {0.f, 0.f, 0.f, 0.f, 0.f, 0.f, 0.f, 0.f};
  int j0 = rowptr[w], j1 = rowptr[w + 1];

  auto proc = [&](f16x8 a8) {
    const f16x2* a2 = (const f16x2*)&a8;
    float s = 0.f;
#pragma unroll
    for (int q = 0; q < 4; ++q) {
      f16x2 e = a2[q] + xr2[q];
      e = __builtin_elementwise_max(e, e * (_Float16)0.2f);
      s = __builtin_amdgcn_fdot2(e, at2[q], s, false);
    }
    s = dpp_add<0xB1>(s);  // xor1
    s = dpp_add<0x4E>(s);  // xor2 -> full 32-ch head logit
    float p = __expf(s);   // shift-invariant: no max subtraction needed in f32
    den += p;
#pragma unroll
    for (int c = 0; c < 8; ++c) acc[c] = fmaf((float)a8[c], p, acc[c]);  // v_fma_mix
  };

  int j = j0 + strm;
  if (j < j1) {
    f16x8 a = *(const f16x8*)(xl + (size_t)adj[j] * 128 + 8 * sub);
    for (j += 4; j < j1; j += 4) {
      f16x8 an = *(const f16x8*)(xl + (size_t)adj[j] * 128 + 8 * sub);
      proc(a);
      a = an;
    }
    proc(a);
  }

  // merge 4 streams: plain sums (shared implicit offset)
  den = swz_add<0x401F>(den);
#pragma unroll
  for (int c = 0; c < 8; ++c) acc[c] = swz_add<0x401F>(acc[c]);
  den += __shfl_xor(den, 32);
#pragma unroll
  for (int c = 0; c < 8; ++c) acc[c] += __shfl_xor(acc[c], 32);

  float inv = 1.f / (den + 1e-16f);
  float v[8], s1 = 0.f, s2 = 0.f;
#pragma unroll
  for (int c = 0; c < 8; ++c) {
    v[c] = fmaf(acc[c], inv, bias[8 * sub + c]);
    s1 += v[c];
    s2 = fmaf(v[c], v[c], s2);
  }
  s1 = dpp_add<0xB1>(s1); s2 = dpp_add<0xB1>(s2);
  s1 = dpp_add<0x4E>(s1); s2 = dpp_add<0x4E>(s2);
  s1 = swz_add<0x101F>(s1); s2 = swz_add<0x101F>(s2);  // xor4
  s1 = swz_add<0x201F>(s1); s2 = swz_add<0x201F>(s2);  // xor8
  float mu = s1 * (1.f / 128.f);
  float var = s2 * (1.f / 128.f) - mu * mu;
  float rs = rsqrtf(var + 1e-5f);
  if (strm == 0) {
    unsigned short o8[8];
#pragma unroll
    for (int c = 0; c < 8; ++c) {
      float r = (v[c] - mu) * rs * g[8 * sub + c] + be[8 * sub + c];
      r = r > 0.f ? r : __expf(r) - 1.f;  // ELU
      o8[c] = f2bf(r);
    }
    *(uint4*)(h_out + (size_t)w * 128 + 8 * sub) = *(const uint4*)o8;
  }
}

// ---------------- fused GAT layer 2: wave/dst, 8 streams x 8 lanes, 8ch/lane ---------------
__global__ __launch_bounds__(256) void gat2(const _Float16* __restrict__ hl,
                                            const _Float16* __restrict__ hr,
                                            const int* __restrict__ rowptr,
                                            const int* __restrict__ adj,
                                            const float* __restrict__ att,
                                            const float* __restrict__ bias,
                                            const float* __restrict__ g,
                                            const float* __restrict__ be,
                                            _Float16* __restrict__ z, int N) {
  int w = blockIdx.x * 4 + (threadIdx.x >> 6);
  int l = threadIdx.x & 63;
  if (w >= N) return;
  int sub = l & 7, strm = l >> 3;
  f16x8 xr8 = *(const f16x8*)(hr + (size_t)w * 64 + 8 * sub);
  const f16x2* xr2 = (const f16x2*)&xr8;
  f16x2 at2[4];
#pragma unroll
  for (int q = 0; q < 4; ++q) {
    at2[q][0] = (_Float16)att[8 * sub + 2 * q];
    at2[q][1] = (_Float16)att[8 * sub + 2 * q + 1];
  }
  float den = 0.f;
  float acc[8] = {0.f, 0.f, 0.f, 0.f, 0.f, 0.f, 0.f, 0.f};
  int j0 = rowptr[w], j1 = rowptr[w + 1];

  auto proc = [&](f16x8 a8) {
    const f16x2* a2 = (const f16x2*)&a8;
    float s = 0.f;
#pragma unroll
    for (int q = 0; q < 4; ++q) {
      f16x2 e = a2[q] + xr2[q];
      e = __builtin_elementwise_max(e, e * (_Float16)0.2f);
      s = __builtin_amdgcn_fdot2(e, at2[q], s, false);
    }
    s = dpp_add<0xB1>(s);
    s = dpp_add<0x4E>(s);
    s = swz_add<0x101F>(s);  // xor4 -> full 64-ch (single-head) logit
    float p = __expf(s);
    den += p;
#pragma unroll
    for (int c = 0; c < 8; ++c) acc[c] = fmaf((float)a8[c], p, acc[c]);
  };

  int j = j0 + strm;
  if (j < j1) {
    f16x8 a = *(const f16x8*)(hl + (size_t)adj[j] * 64 + 8 * sub);
    for (j += 8; j < j1; j += 8) {
      f16x8 an = *(const f16x8*)(hl + (size_t)adj[j] * 64 + 8 * sub);
      proc(a);
      a = an;
    }
    proc(a);
  }

  den = swz_add<0x201F>(den);
#pragma unroll
  for (int c = 0; c < 8; ++c) acc[c] = swz_add<0x201F>(acc[c]);
  den = swz_add<0x401F>(den);
#pragma unroll
  for (int c = 0; c < 8; ++c) acc[c] = swz_add<0x401F>(acc[c]);
  den += __shfl_xor(den, 32);
#pragma unroll
  for (int c = 0; c < 8; ++c) acc[c] += __shfl_xor(acc[c], 32);

  float inv = 1.f / (den + 1e-16f);
  float v[8], s1 = 0.f, s2 = 0.f;
#pragma unroll
  for (int c = 0; c < 8; ++c) {
    v[c] = fmaf(acc[c], inv, bias[8 * sub + c]);
    s1 += v[c];
    s2 = fmaf(v[c], v[c], s2);
  }
  s1 = dpp_add<0xB1>(s1); s2 = dpp_add<0xB1>(s2);
  s1 = dpp_add<0x4E>(s1); s2 = dpp_add<0x4E>(s2);
  s1 = swz_add<0x101F>(s1); s2 = swz_add<0x101F>(s2);
  float mu = s1 * (1.f / 64.f);
  float var = s2 * (1.f / 64.f) - mu * mu;
  float rs = rsqrtf(var + 1e-5f);
  if (strm == 0) {
    f16x8 zz;
#pragma unroll
    for (int c = 0; c < 8; ++c)
      zz[c] = (_Float16)((v[c] - mu) * rs * g[8 * sub + c] + be[8 * sub + c]);
    *(f16x8*)(z + (size_t)w * 64 + 8 * sub) = zz;
  }
}

// ---------------- decode: 8 pairs per wave, 8 lanes per pair, fdot2 ----------------
__global__ __launch_bounds__(256) void decode(const _Float16* __restrict__ z,
                                              const int* __restrict__ eli,
                                              float* __restrict__ out, int EL) {
  int wv = threadIdx.x >> 6, l = threadIdx.x & 63;
  int sub = l & 7;
  int pidx = (blockIdx.x * 4 + wv) * 8 + (l >> 3);
  if (pidx >= EL) return;
  int a = eli[pidx], b = eli[EL + pidx];
  f16x8 za = *(const f16x8*)(z + (size_t)a * 64 + 8 * sub);
  f16x8 zb = *(const f16x8*)(z + (size_t)b * 64 + 8 * sub);
  const f16x2* za2 = (const f16x2*)&za;
  const f16x2* zb2 = (const f16x2*)&zb;
  float p = 0.f;
#pragma unroll
  for (int q = 0; q < 4; ++q) p = __builtin_amdgcn_fdot2(za2[q], zb2[q], p, false);
  p = dpp_add<0xB1>(p);
  p = dpp_add<0x4E>(p);
  p = swz_add<0x101F>(p);
  if (sub == 0) out[pidx] = p;
}

extern "C" void kernel_launch(void* const* d_in, const int* in_sizes, int n_in, void* d_out,
                              int out_size, void* d_ws, size_t ws_size, hipStream_t stream) {
  const float* x = (const float*)d_in[0];
  const int* ei = (const int*)d_in[1];
  const int* eli = (const int*)d_in[2];
  const float* W1l = (const float*)d_in[3];
  const float* b1l = (const float*)d_in[4];
  const float* W1r = (const float*)d_in[5];
  const float* b1r = (const float*)d_in[6];
  const float* att1 = (const float*)d_in[7];
  const float* bias1 = (const float*)d_in[8];
  const float* g1 = (const float*)d_in[9];
  const float* be1 = (const float*)d_in[10];
  const float* W2l = (const float*)d_in[11];
  const float* b2l = (const float*)d_in[12];
  const float* W2r = (const float*)d_in[13];
  const float* b2r = (const float*)d_in[14];
  const float* att2 = (const float*)d_in[15];
  const float* bias2 = (const float*)d_in[16];
  const float* g2 = (const float*)d_in[17];
  const float* be2 = (const float*)d_in[18];

  const int N = in_sizes[0] / 128;
  const int E = in_sizes[1] / 2;
  const int EL = in_sizes[2] / 2;
  const int ET = E + N;

  char* base = (char*)d_ws;
  _Float16* xl16 = (_Float16*)base;                                  // N*128 f16
  _Float16* xr16 = (_Float16*)(base + (size_t)N * 256);              // N*128 f16
  unsigned short* h_bf = (unsigned short*)(base + (size_t)N * 512);  // N*128 bf16
  _Float16* hl16 = (_Float16*)(base + (size_t)N * 768);              // N*64 f16
  _Float16* hr16 = (_Float16*)(base + (size_t)N * 896);              // N*64 f16
  _Float16* z16 = (_Float16*)(base + (size_t)N * 1024);              // N*64 f16
  int* ib = (int*)(base + (size_t)N * 1152);
  int* cnt = ib;
  int* cur = ib + N;
  int* rowptr = ib + 2 * N;
  int* part = ib + 3 * N + 2;
  int* adj = ib + 3 * N + 258;
  size_t ints_bytes = ((size_t)(3 * N + 258) + (size_t)ET) * 4;
  unsigned short* wbuf =
      (unsigned short*)(base + (((size_t)N * 1152 + ints_bytes + 255) & ~(size_t)255));

  const int n4 = (N + 3) / 4;
  prep0<<<64, 256, 0, stream>>>(W1l, W1r, W2l, W2r, wbuf, (int4*)cnt, n4);

  const int eB = (ET + 255) / 256;
  const int Mtiles = (N + 15) / 16;
  const int pBlocks = (Mtiles + 3) / 4;
  projdeg<<<pBlocks + eB, 256, 0, stream>>>(x, wbuf, b1l, b1r, xl16, xr16, Mtiles, pBlocks, ei,
                                            cnt, E, ET);

  const int nB = (N + 255) / 256;
  scanA<<<nB, 256, 0, stream>>>(cnt, part, N);
  scanB<<<1, 256, 0, stream>>>(part, rowptr, nB, N);
  scanC<<<nB, 256, 0, stream>>>(cnt, part, rowptr, cur, N);

  const int Nper = (N + 7) / 8;
  scatter_part<<<8 * eB, 256, 0, stream>>>(ei, cur, adj, E, ET, Nper);

  const int gB = (N + 3) / 4;
  gat1<<<gB, 256, 0, stream>>>(xl16, xr16, h_bf, rowptr, adj, att1, bias1, g1, be1, N);

  proj2<<<pBlocks, 256, 0, stream>>>(h_bf, wbuf + 32768, b2l, b2r, hl16, hr16, Mtiles);

  gat2<<<gB, 256, 0, stream>>>(hl16, hr16, rowptr, adj, att2, bias2, g2, be2, z16, N);

  const int dBlocks = (EL + 31) / 32;
  decode<<<dBlocks, 256, 0, stream>>>(z16, eli, (float*)d_out, EL);
}

// Round 22
// 138.440 us; speedup vs baseline: 1.3550x; 1.2946x over previous
//
#include <hip/hip_runtime.h>
#include <hip/hip_bf16.h>

// GATv2 link predictor: N=50000, E=800000 (+N self loops), IN=128, HID=32, HEADS=4, OUT=64
// f32 in/out. Fused GAT layers, shift-invariant softmax, pk-f16 logit math, f32 accum.
// bf16 MFMA projections (swapped operand, pre-swizzled W image, LDS-transpose stores).
// Round 22: SLOTTED CSR — adj[dst*64+pos], pos=atomicAdd(cnt[dst],1), single atomic pass
// fused into projdeg. Eliminates deg-count pass + scanA/B/C + standalone scatter (the
// device-scope atomics are memory-side RMWs — invariant to partitioning/occupancy/coalescing
// per r18/r19/r21 — so pay the toll ONCE, not twice).

#define DEVFN __device__ __forceinline__

typedef __attribute__((ext_vector_type(4))) float f32x4;
typedef __attribute__((ext_vector_type(8))) short bf16x8;
typedef _Float16 f16x2 __attribute__((ext_vector_type(2)));
typedef _Float16 f16x8 __attribute__((ext_vector_type(8)));

DEVFN unsigned short f2bf(float f) {  // RNE f32->bf16
  unsigned u = __float_as_uint(f);
  return (unsigned short)((u + 0x7fffu + ((u >> 16) & 1u)) >> 16);
}

DEVFN f16x2 pkrtz(float a, float b) {
  auto r = __builtin_amdgcn_cvt_pkrtz(a, b);
  union { decltype(r) s; f16x2 d; } u;
  u.s = r;
  return u.d;
}

template <int CTRL>
DEVFN float dpp_add(float s) {
  int x = __builtin_amdgcn_update_dpp(0, __float_as_int(s), CTRL, 0xF, 0xF, true);
  return s + __int_as_float(x);
}
template <int OFF>
DEVFN float swz_add(float s) {
  int x = __builtin_amdgcn_ds_swizzle(__float_as_int(s), OFF);
  return s + __int_as_float(x);
}

DEVFN bf16x8 load_frag(const float* p) {
  f32x4 u = *(const f32x4*)p;
  f32x4 v = *(const f32x4*)(p + 4);
  union { unsigned r[4]; bf16x8 h; } o;
  asm("v_cvt_pk_bf16_f32 %0, %1, %2" : "=v"(o.r[0]) : "v"(u[0]), "v"(u[1]));
  asm("v_cvt_pk_bf16_f32 %0, %1, %2" : "=v"(o.r[1]) : "v"(u[2]), "v"(u[3]));
  asm("v_cvt_pk_bf16_f32 %0, %1, %2" : "=v"(o.r[2]) : "v"(v[0]), "v"(v[1]));
  asm("v_cvt_pk_bf16_f32 %0, %1, %2" : "=v"(o.r[3]) : "v"(v[2]), "v"(v[3]));
  return o.h;
}
DEVFN bf16x8 load_frag(const unsigned short* p) { return *(const bf16x8*)p; }

// ---------------- shared projection body: MFMA + LDS-transpose coalesced stores ----------
template <typename TIN, int DOUT>
DEVFN void proj_body(const TIN* __restrict__ X, const unsigned short* __restrict__ wsrc,
                     const float* __restrict__ Ba, const float* __restrict__ Bb,
                     _Float16* __restrict__ Ya, _Float16* __restrict__ Yb, int Mtiles,
                     int blockId, char* smem) {
  constexpr int NPM = DOUT / 16;
  constexpr unsigned MATB = DOUT * 256;
  constexpr int ROWB = DOUT * 2;
  constexpr int PADROW = ROWB + 16;
  unsigned short* sW = (unsigned short*)smem;
  const int t = threadIdx.x;
  const int l = t & 63, wv = t >> 6;
  const int mt = blockId * 4 + wv;
  const bool active = mt < Mtiles;
  const int r15 = l & 15, kq = l >> 4;
  char* trw = smem + MATB + wv * (16 * PADROW);

  bf16x8 a0[4];
  if (active) {
    const TIN* px = X + ((size_t)(mt * 16 + r15)) * 128 + kq * 8;
#pragma unroll
    for (int ks = 0; ks < 4; ++ks) a0[ks] = load_frag(px + ks * 32);
  }

#pragma unroll
  for (int mat = 0; mat < 2; ++mat) {
    if (mat) __syncthreads();
    {
      const char* gsrc = (const char*)wsrc + (unsigned)mat * MATB;
      for (unsigned off = t * 16; off < MATB; off += 256 * 16)
        *(uint4*)(smem + off) = *(const uint4*)(gsrc + off);
    }
    __syncthreads();
    if (active) {
      const float* Bv = mat ? Bb : Ba;
      _Float16* Y = mat ? Yb : Ya;
#pragma unroll
      for (int q = 0; q < NPM; ++q) {
        const int o = q * 16 + r15;
        bf16x8 b[4];
#pragma unroll
        for (int ks = 0; ks < 4; ++ks) {
          unsigned byteoff =
              ((unsigned)(o * 256 + (ks * 32 + kq * 8) * 2)) ^ ((unsigned)(o & 7) << 4);
          b[ks] = *(const bf16x8*)((const char*)sW + byteoff);
        }
        f32x4 c0 = {0.f, 0.f, 0.f, 0.f};
#pragma unroll
        for (int ks = 0; ks < 4; ++ks)
          c0 = __builtin_amdgcn_mfma_f32_16x16x32_bf16(b[ks], a0[ks], c0, 0, 0, 0);
        const int obase = q * 16 + 4 * kq;
        float4 b4 = *(const float4*)(Bv + obase);
        union { f16x2 h[2]; uint2 u; } pk;
        pk.h[0] = pkrtz(c0[0] + b4.x, c0[1] + b4.y);
        pk.h[1] = pkrtz(c0[2] + b4.z, c0[3] + b4.w);
        *(uint2*)(trw + r15 * PADROW + obase * 2) = pk.u;
      }
      char* gdst = (char*)(Y + (size_t)mt * 16 * DOUT);
      constexpr int ITERS = (16 * ROWB) / (64 * 16);
#pragma unroll
      for (int i = 0; i < ITERS; ++i) {
        int off = l * 16 + i * 1024;
        *(uint4*)(gdst + off) = *(const uint4*)(trw + (off / ROWB) * PADROW + (off % ROWB));
      }
    }
  }
}

// ---------------- prep0: W->bf16 swizzled image + zero cnt ----------------
__global__ __launch_bounds__(256) void prep0(const float* __restrict__ W1l,
                                             const float* __restrict__ W1r,
                                             const float* __restrict__ W2l,
                                             const float* __restrict__ W2r,
                                             unsigned short* __restrict__ wbuf,
                                             int4* __restrict__ cnt4, int n4) {
  int t = blockIdx.x * 256 + threadIdx.x;
  if (t < 16384) {  // W1: [128][128]
    int k = t >> 7, o = t & 127;
    unsigned off = ((unsigned)(o * 256 + k * 2)) ^ ((unsigned)(o & 7) << 4);
    wbuf[off >> 1] = f2bf(W1l[t]);
    wbuf[16384 + (off >> 1)] = f2bf(W1r[t]);
  }
  if (t < 8192) {  // W2: [128][64]
    int k = t >> 6, o = t & 63;
    unsigned off = ((unsigned)(o * 256 + k * 2)) ^ ((unsigned)(o & 7) << 4);
    wbuf[32768 + (off >> 1)] = f2bf(W2l[t]);
    wbuf[40960 + (off >> 1)] = f2bf(W2r[t]);
  }
  if (t < n4) cnt4[t] = make_int4(0, 0, 0, 0);
}

// ---------------- projscat: proj1 + slotted-CSR scatter (single atomic pass) --------------
// blocks [0,pBlocks): projection. blocks [pBlocks, pBlocks+8*eB): scatter, XCD-partitioned:
// block d handles dst partition d&7; adj[dst*64+pos], pos = atomicAdd(cnt[dst],1).
__global__ __launch_bounds__(256) void projscat(const float* __restrict__ X,
                                                const unsigned short* __restrict__ wsrc,
                                                const float* __restrict__ Ba,
                                                const float* __restrict__ Bb,
                                                _Float16* __restrict__ Ya,
                                                _Float16* __restrict__ Yb, int Mtiles,
                                                int pBlocks, const int* __restrict__ ei,
                                                int* __restrict__ cnt, int* __restrict__ adj,
                                                int E, int ET, int Nper) {
  __shared__ char smem[128 * 256 + 4 * 16 * (256 + 16)];
  if (blockIdx.x >= pBlocks) {  // scatter blocks (exit before any barrier)
    int d = blockIdx.x - pBlocks;
    int part = d & 7;
    int t = (d >> 3) * 256 + threadIdx.x;
    if (t < ET) {
      int dst = (t < E) ? ei[E + t] : (t - E);
      if ((unsigned)(dst - part * Nper) < (unsigned)Nper) {
        int src = (t < E) ? ei[t] : dst;
        int pos = atomicAdd(&cnt[dst], 1);
        if (pos < 64) adj[((size_t)dst << 6) | pos] = src;
      }
    }
    return;
  }
  proj_body<float, 128>(X, wsrc, Ba, Bb, Ya, Yb, Mtiles, blockIdx.x, smem);
}

// ---------------- proj2 ----------------
__global__ __launch_bounds__(256) void proj2(const unsigned short* __restrict__ X,
                                             const unsigned short* __restrict__ wsrc,
                                             const float* __restrict__ Ba,
                                             const float* __restrict__ Bb,
                                             _Float16* __restrict__ Ya,
                                             _Float16* __restrict__ Yb, int Mtiles) {
  __shared__ char smem[64 * 256 + 4 * 16 * (128 + 16)];
  proj_body<unsigned short, 64>(X, wsrc, Ba, Bb, Ya, Yb, Mtiles, blockIdx.x, smem);
}

// ---------------- fused GAT layer 1: wave/dst, 4 streams x 16 lanes, 8ch/lane --------------
// Slotted CSR: edges of dst w live at adj[w*64 .. w*64+cnt[w]).
// head = sub>>2; per-head logit = xor1+xor2 over subs {4h..4h+3} = ch [32h,32h+32).
__global__ __launch_bounds__(256) void gat1(const _Float16* __restrict__ xl,
                                            const _Float16* __restrict__ xr,
                                            unsigned short* __restrict__ h_out,
                                            const int* __restrict__ cnt,
                                            const int* __restrict__ adj,
                                            const float* __restrict__ att,
                                            const float* __restrict__ bias,
                                            const float* __restrict__ g,
                                            const float* __restrict__ be, int N) {
  int w = blockIdx.x * 4 + (threadIdx.x >> 6);
  int l = threadIdx.x & 63;
  if (w >= N) return;
  int sub = l & 15, strm = l >> 4;
  f16x8 xr8 = *(const f16x8*)(xr + (size_t)w * 128 + 8 * sub);
  const f16x2* xr2 = (const f16x2*)&xr8;
  f16x2 at2[4];
#pragma unroll
  for (int q = 0; q < 4; ++q) {
    at2[q][0] = (_Float16)att[8 * sub + 2 * q];
    at2[q][1] = (_Float16)att[8 * sub + 2 * q + 1];
  }
  float den = 0.f;
  float acc[8] = {0.f, 0.f, 0.f, 0.f, 0.f, 0.f, 0.f, 0.f};
  int deg = cnt[w];
  deg = deg < 64 ? deg : 64;
  int j0 = w << 6, j1 = j0 + deg;

  auto proc = [&](f16x8 a8) {
    const f16x2* a2 = (const f16x2*)&a8;
    float s = 0.f;
#pragma unroll
    for (int q = 0; q < 4; ++q) {
      f16x2 e = a2[q] + xr2[q];
      e = __builtin_elementwise_max(e, e * (_Float16)0.2f);
      s = __builtin_amdgcn_fdot2(e, at2[q], s, false);
    }
    s = dpp_add<0xB1>(s);  // xor1
    s = dpp_add<0x4E>(s);  // xor2 -> full 32-ch head logit
    float p = __expf(s);   // shift-invariant: no max subtraction needed in f32
    den += p;
#pragma unroll
    for (int c = 0; c < 8; ++c) acc[c] = fmaf((float)a8[c], p, acc[c]);  // v_fma_mix
  };

  int j = j0 + strm;
  if (j < j1) {
    f16x8 a = *(const f16x8*)(xl + (size_t)adj[j] * 128 + 8 * sub);
    for (j += 4; j < j1; j += 4) {
      f16x8 an = *(const f16x8*)(xl + (size_t)adj[j] * 128 + 8 * sub);
      proc(a);
      a = an;
    }
    proc(a);
  }

  // merge 4 streams: plain sums (shared implicit offset)
  den = swz_add<0x401F>(den);
#pragma unroll
  for (int c = 0; c < 8; ++c) acc[c] = swz_add<0x401F>(acc[c]);
  den += __shfl_xor(den, 32);
#pragma unroll
  for (int c = 0; c < 8; ++c) acc[c] += __shfl_xor(acc[c], 32);

  float inv = 1.f / (den + 1e-16f);
  float v[8], s1 = 0.f, s2 = 0.f;
#pragma unroll
  for (int c = 0; c < 8; ++c) {
    v[c] = fmaf(acc[c], inv, bias[8 * sub + c]);
    s1 += v[c];
    s2 = fmaf(v[c], v[c], s2);
  }
  s1 = dpp_add<0xB1>(s1); s2 = dpp_add<0xB1>(s2);
  s1 = dpp_add<0x4E>(s1); s2 = dpp_add<0x4E>(s2);
  s1 = swz_add<0x101F>(s1); s2 = swz_add<0x101F>(s2);  // xor4
  s1 = swz_add<0x201F>(s1); s2 = swz_add<0x201F>(s2);  // xor8
  float mu = s1 * (1.f / 128.f);
  float var = s2 * (1.f / 128.f) - mu * mu;
  float rs = rsqrtf(var + 1e-5f);
  if (strm == 0) {
    unsigned short o8[8];
#pragma unroll
    for (int c = 0; c < 8; ++c) {
      float r = (v[c] - mu) * rs * g[8 * sub + c] + be[8 * sub + c];
      r = r > 0.f ? r : __expf(r) - 1.f;  // ELU
      o8[c] = f2bf(r);
    }
    *(uint4*)(h_out + (size_t)w * 128 + 8 * sub) = *(const uint4*)o8;
  }
}

// ---------------- fused GAT layer 2: wave/dst, 8 streams x 8 lanes, 8ch/lane ---------------
__global__ __launch_bounds__(256) void gat2(const _Float16* __restrict__ hl,
                                            const _Float16* __restrict__ hr,
                                            const int* __restrict__ cnt,
                                            const int* __restrict__ adj,
                                            const float* __restrict__ att,
                                            const float* __restrict__ bias,
                                            const float* __restrict__ g,
                                            const float* __restrict__ be,
                                            _Float16* __restrict__ z, int N) {
  int w = blockIdx.x * 4 + (threadIdx.x >> 6);
  int l = threadIdx.x & 63;
  if (w >= N) return;
  int sub = l & 7, strm = l >> 3;
  f16x8 xr8 = *(const f16x8*)(hr + (size_t)w * 64 + 8 * sub);
  const f16x2* xr2 = (const f16x2*)&xr8;
  f16x2 at2[4];
#pragma unroll
  for (int q = 0; q < 4; ++q) {
    at2[q][0] = (_Float16)att[8 * sub + 2 * q];
    at2[q][1] = (_Float16)att[8 * sub + 2 * q + 1];
  }
  float den = 0.f;
  float acc[8] = {0.f, 0.f, 0.f, 0.f, 0.f, 0.f, 0.f, 0.f};
  int deg = cnt[w];
  deg = deg < 64 ? deg : 64;
  int j0 = w << 6, j1 = j0 + deg;

  auto proc = [&](f16x8 a8) {
    const f16x2* a2 = (const f16x2*)&a8;
    float s = 0.f;
#pragma unroll
    for (int q = 0; q < 4; ++q) {
      f16x2 e = a2[q] + xr2[q];
      e = __builtin_elementwise_max(e, e * (_Float16)0.2f);
      s = __builtin_amdgcn_fdot2(e, at2[q], s, false);
    }
    s = dpp_add<0xB1>(s);
    s = dpp_add<0x4E>(s);
    s = swz_add<0x101F>(s);  // xor4 -> full 64-ch (single-head) logit
    float p = __expf(s);
    den += p;
#pragma unroll
    for (int c = 0; c < 8; ++c) acc[c] = fmaf((float)a8[c], p, acc[c]);
  };

  int j = j0 + strm;
  if (j < j1) {
    f16x8 a = *(const f16x8*)(hl + (size_t)adj[j] * 64 + 8 * sub);
    for (j += 8; j < j1; j += 8) {
      f16x8 an = *(const f16x8*)(hl + (size_t)adj[j] * 64 + 8 * sub);
      proc(a);
      a = an;
    }
    proc(a);
  }

  den = swz_add<0x201F>(den);
#pragma unroll
  for (int c = 0; c < 8; ++c) acc[c] = swz_add<0x201F>(acc[c]);
  den = swz_add<0x401F>(den);
#pragma unroll
  for (int c = 0; c < 8; ++c) acc[c] = swz_add<0x401F>(acc[c]);
  den += __shfl_xor(den, 32);
#pragma unroll
  for (int c = 0; c < 8; ++c) acc[c] += __shfl_xor(acc[c], 32);

  float inv = 1.f / (den + 1e-16f);
  float v[8], s1 = 0.f, s2 = 0.f;
#pragma unroll
  for (int c = 0; c < 8; ++c) {
    v[c] = fmaf(acc[c], inv, bias[8 * sub + c]);
    s1 += v[c];
    s2 = fmaf(v[c], v[c], s2);
  }
  s1 = dpp_add<0xB1>(s1); s2 = dpp_add<0xB1>(s2);
  s1 = dpp_add<0x4E>(s1); s2 = dpp_add<0x4E>(s2);
  s1 = swz_add<0x101F>(s1); s2 = swz_add<0x101F>(s2);
  float mu = s1 * (1.f / 64.f);
  float var = s2 * (1.f / 64.f) - mu * mu;
  float rs = rsqrtf(var + 1e-5f);
  if (strm == 0) {
    f16x8 zz;
#pragma unroll
    for (int c = 0; c < 8; ++c)
      zz[c] = (_Float16)((v[c] - mu) * rs * g[8 * sub + c] + be[8 * sub + c]);
    *(f16x8*)(z + (size_t)w * 64 + 8 * sub) = zz;
  }
}

// ---------------- decode: 8 pairs per wave, 8 lanes per pair, fdot2 ----------------
__global__ __launch_bounds__(256) void decode(const _Float16* __restrict__ z,
                                              const int* __restrict__ eli,
                                              float* __restrict__ out, int EL) {
  int wv = threadIdx.x >> 6, l = threadIdx.x & 63;
  int sub = l & 7;
  int pidx = (blockIdx.x * 4 + wv) * 8 + (l >> 3);
  if (pidx >= EL) return;
  int a = eli[pidx], b = eli[EL + pidx];
  f16x8 za = *(const f16x8*)(z + (size_t)a * 64 + 8 * sub);
  f16x8 zb = *(const f16x8*)(z + (size_t)b * 64 + 8 * sub);
  const f16x2* za2 = (const f16x2*)&za;
  const f16x2* zb2 = (const f16x2*)&zb;
  float p = 0.f;
#pragma unroll
  for (int q = 0; q < 4; ++q) p = __builtin_amdgcn_fdot2(za2[q], zb2[q], p, false);
  p = dpp_add<0xB1>(p);
  p = dpp_add<0x4E>(p);
  p = swz_add<0x101F>(p);
  if (sub == 0) out[pidx] = p;
}

extern "C" void kernel_launch(void* const* d_in, const int* in_sizes, int n_in, void* d_out,
                              int out_size, void* d_ws, size_t ws_size, hipStream_t stream) {
  const float* x = (const float*)d_in[0];
  const int* ei = (const int*)d_in[1];
  const int* eli = (const int*)d_in[2];
  const float* W1l = (const float*)d_in[3];
  const float* b1l = (const float*)d_in[4];
  const float* W1r = (const float*)d_in[5];
  const float* b1r = (const float*)d_in[6];
  const float* att1 = (const float*)d_in[7];
  const float* bias1 = (const float*)d_in[8];
  const float* g1 = (const float*)d_in[9];
  const float* be1 = (const float*)d_in[10];
  const float* W2l = (const float*)d_in[11];
  const float* b2l = (const float*)d_in[12];
  const float* W2r = (const float*)d_in[13];
  const float* b2r = (const float*)d_in[14];
  const float* att2 = (const float*)d_in[15];
  const float* bias2 = (const float*)d_in[16];
  const float* g2 = (const float*)d_in[17];
  const float* be2 = (const float*)d_in[18];

  const int N = in_sizes[0] / 128;
  const int E = in_sizes[1] / 2;
  const int EL = in_sizes[2] / 2;
  const int ET = E + N;

  char* base = (char*)d_ws;
  _Float16* xl16 = (_Float16*)base;                                  // N*128 f16
  _Float16* xr16 = (_Float16*)(base + (size_t)N * 256);              // N*128 f16
  unsigned short* h_bf = (unsigned short*)(base + (size_t)N * 512);  // N*128 bf16
  _Float16* hl16 = (_Float16*)(base + (size_t)N * 768);              // N*64 f16
  _Float16* hr16 = (_Float16*)(base + (size_t)N * 896);              // N*64 f16
  _Float16* z16 = (_Float16*)(base + (size_t)N * 1024);              // N*64 f16
  int* ib = (int*)(base + (size_t)N * 1152);
  int* cnt = ib;            // N
  int* adj = ib + N;        // N*64 (slotted)
  size_t ints_bytes = ((size_t)N * 65) * 4;
  unsigned short* wbuf =
      (unsigned short*)(base + (((size_t)N * 1152 + ints_bytes + 255) & ~(size_t)255));

  const int n4 = (N + 3) / 4;
  prep0<<<64, 256, 0, stream>>>(W1l, W1r, W2l, W2r, wbuf, (int4*)cnt, n4);

  const int eB = (ET + 255) / 256;
  const int Mtiles = (N + 15) / 16;
  const int pBlocks = (Mtiles + 3) / 4;
  const int Nper = (N + 7) / 8;
  projscat<<<pBlocks + 8 * eB, 256, 0, stream>>>(x, wbuf, b1l, b1r, xl16, xr16, Mtiles, pBlocks,
                                                 ei, cnt, adj, E, ET, Nper);

  const int gB = (N + 3) / 4;
  gat1<<<gB, 256, 0, stream>>>(xl16, xr16, h_bf, cnt, adj, att1, bias1, g1, be1, N);

  proj2<<<pBlocks, 256, 0, stream>>>(h_bf, wbuf + 32768, b2l, b2r, hl16, hr16, Mtiles);

  gat2<<<gB, 256, 0, stream>>>(hl16, hr16, cnt, adj, att2, bias2, g2, be2, z16, N);

  const int dBlocks = (EL + 31) / 32;
  decode<<<dBlocks, 256, 0, stream>>>(z16, eli, (float*)d_out, EL);
}